// Round 7
// baseline (5295.990 us; speedup 1.0000x reference)
//
#include <hip/hip_runtime.h>
#include <cstdint>
#include <cstddef>

namespace {

constexpr int NN   = 200000;   // nodes
constexpr int NE   = 800000;   // edges
constexpr int NG   = 4096;     // graphs
constexpr int MAXD = 5;

constexpr int BM = 64;
constexpr int BN = 128;
constexpr int KT = 32;
constexpr int NBLK  = (NN + BM - 1) / BM + 6;   // 3125 + 6 = 3131 (bucket padding)
constexpr int PERMN = NBLK * BM;                // 200384

// ---------------- init / diagnostic ----------------

__global__ void k_memset32(int* __restrict__ p, int v, int n) {
    int i = blockIdx.x * 256 + threadIdx.x;
    if (i < n) p[i] = v;
}

__global__ void k_report(float* __restrict__ outp, float v, int n) {
    int i = blockIdx.x * 256 + threadIdx.x;
    if (i < n) outp[i] = v;
}

// ---------------- graph preprocessing ----------------

__global__ void k_count_deg(const int* __restrict__ dst, int* __restrict__ deg) {
    int e = blockIdx.x * 256 + threadIdx.x;
    if (e < NE) atomicAdd(&deg[dst[e]], 1);
}

__global__ void k_scan_part(const int* __restrict__ deg, int* __restrict__ part) {
    __shared__ int s[256];
    int t = threadIdx.x, i = blockIdx.x * 256 + t;
    s[t] = (i < NN) ? deg[i] : 0;
    __syncthreads();
    for (int st = 128; st > 0; st >>= 1) {
        if (t < st) s[t] += s[t + st];
        __syncthreads();
    }
    if (t == 0) part[blockIdx.x] = s[0];
}

__global__ void k_scan_single(int* __restrict__ part, int nb) {
    __shared__ int s[1024];
    int t = threadIdx.x;
    int v0 = (t < nb) ? part[t] : 0;
    s[t] = v0;
    __syncthreads();
    for (int off = 1; off < 1024; off <<= 1) {
        int v = (t >= off) ? s[t - off] : 0;
        __syncthreads();
        s[t] += v;
        __syncthreads();
    }
    if (t < nb) part[t] = s[t] - v0;   // exclusive prefix of block sums
}

__global__ void k_scan_final(const int* __restrict__ deg, const int* __restrict__ part,
                             int* __restrict__ row_ptr, int* __restrict__ cursor) {
    __shared__ int s[256];
    int t = threadIdx.x, i = blockIdx.x * 256 + t;
    int v0 = (i < NN) ? deg[i] : 0;
    s[t] = v0;
    __syncthreads();
    for (int off = 1; off < 256; off <<= 1) {
        int v = (t >= off) ? s[t - off] : 0;
        __syncthreads();
        s[t] += v;
        __syncthreads();
    }
    if (i < NN) {
        int excl = s[t] - v0 + part[blockIdx.x];
        row_ptr[i] = excl;
        cursor[i]  = excl;
        if (i == NN - 1) row_ptr[NN] = excl + v0;
    }
}

__global__ void k_fill_csr(const int* __restrict__ src, const int* __restrict__ dst,
                           int* __restrict__ cursor, int* __restrict__ col) {
    int e = blockIdx.x * 256 + threadIdx.x;
    if (e < NE) {
        int d = dst[e];
        int slot = atomicAdd(&cursor[d], 1);
        col[slot] = src[e];
    }
}

__global__ void k_bucket_count(const int* __restrict__ deg, int* __restrict__ bcnt) {
    int i = blockIdx.x * 256 + threadIdx.x;
    if (i < NN) atomicAdd(&bcnt[min(deg[i], MAXD)], 1);
}

__global__ void k_bucket_scan(const int* __restrict__ bcnt, int* __restrict__ bpad) {
    if (threadIdx.x == 0 && blockIdx.x == 0) {
        int off = 0;
        for (int b = 0; b < 6; b++) {
            bpad[b] = off;
            off += ((bcnt[b] + BM - 1) / BM) * BM;
        }
        bpad[6] = off;
    }
}

__global__ void k_scatter(const int* __restrict__ deg, const int* __restrict__ bpad,
                          int* __restrict__ bcur, int* __restrict__ perm) {
    int i = blockIdx.x * 256 + threadIdx.x;
    if (i < NN) {
        int b = min(deg[i], MAXD);
        int pos = atomicAdd(&bcur[b], 1);
        perm[bpad[b] + pos] = i;
    }
}

// ---------------- layer-2a: plain neighbor-sum aggregate ----------------

__global__ void k_aggregate128(const float* __restrict__ hin, const int* __restrict__ row_ptr,
                               const int* __restrict__ col, float* __restrict__ msg) {
    int node = blockIdx.x * 4 + (threadIdx.x >> 6);
    int lane = threadIdx.x & 63;
    int s = row_ptr[node], e = row_ptr[node + 1];
    float2 acc = make_float2(0.f, 0.f);
    for (int p = s; p < e; p++) {
        const float2 v = *(const float2*)(hin + (size_t)col[p] * 128 + lane * 2);
        acc.x += v.x; acc.y += v.y;
    }
    *(float2*)(msg + (size_t)node * 128 + lane * 2) = acc;
}

// ---------------- fused aggregate + transform (register-gather) ----------------

// out[i] = [sum_{j->i} hin[j], hin[i]] @ [Wl[d]; Wr[d]] + bl[d], d = bucket(i).
// Neighbor gather hoisted out of the K-loop into mreg[] (one edge-list walk).
// __launch_bounds__(256,3): ~170-VGPR budget so mreg NEVER spills to scratch
// (round-6 bug: default bounds capped at 64 VGPR -> 400 MB scratch traffic).
// Lane B-columns are two chunks {4tx, 64+4tx} (2-way LDS bank pattern = free).
// POOL_FUSE: no h store; rows atomically accumulated into pool[batch[node]].
// Epilogue always banks this chunk's Wf contribution into per-node logits.
template <int C0, int C1, int COUT, bool POOL_FUSE>
__launch_bounds__(256, 3)
__global__ void k_transform(const float* __restrict__ hin0, const float* __restrict__ hin1,
                            const int* __restrict__ row_ptr, const int* __restrict__ col,
                            const float* __restrict__ Wl, const float* __restrict__ bl,
                            const float* __restrict__ Wr, const float* __restrict__ Wf,
                            const int* __restrict__ perm, const int* __restrict__ deg,
                            const int* __restrict__ batch,
                            float* __restrict__ out0, float* __restrict__ pool,
                            float* __restrict__ logits, int wf_off) {
    constexpr int CIN = C0 + C1;
    constexpr int NW0 = C0 / 32;    // msg windows served by hin0
    constexpr int NW  = CIN / 32;   // total msg windows (= msg K-tiles)
    __shared__ float As[KT][BM];
    __shared__ float Bs[KT][BN];
    __shared__ int rowid[BM];

    const int t  = threadIdx.x;
    const int m0 = blockIdx.x * BM;
    const int n0 = blockIdx.y * BN;

    if (t < BM) rowid[t] = perm[m0 + t];
    __syncthreads();
    if (rowid[0] < 0) return;  // fully-padded block (uniform exit)

    const int d = min(deg[rowid[0]], MAXD);
    const float* WlB = Wl + (size_t)d * CIN * COUT;
    const float* WrB = Wr + (size_t)d * CIN * COUT;

    const int am = t & 63, aq = t >> 6;
    const int anode = rowid[am];
    int es = 0, ee = 0;
    if (anode >= 0) { es = row_ptr[anode]; ee = row_ptr[anode + 1]; }
    const int bn = (t & 31) * 4, bk = t >> 5;
    const int tx = t & 15, ty = t >> 4;

    // ---- pre-gather: one edge-list walk fills all owned msg slices ----
    float mreg[8 * NW];
#pragma unroll
    for (int i = 0; i < 8 * NW; i++) mreg[i] = 0.f;
    for (int p = es; p < ee; p++) {
        const int j = col[p];
        const float* r0 = hin0 + (size_t)j * C0 + 4 * aq;
#pragma unroll
        for (int ti = 0; ti < NW0; ti++) {
            const float4 a = *(const float4*)(r0 + 32 * ti);
            const float4 b = *(const float4*)(r0 + 32 * ti + 16);
            mreg[8*ti+0] += a.x; mreg[8*ti+1] += a.y;
            mreg[8*ti+2] += a.z; mreg[8*ti+3] += a.w;
            mreg[8*ti+4] += b.x; mreg[8*ti+5] += b.y;
            mreg[8*ti+6] += b.z; mreg[8*ti+7] += b.w;
        }
        if constexpr (C1 > 0) {
            const float* r1 = hin1 + (size_t)j * C1 + 4 * aq;
#pragma unroll
            for (int ti = NW0; ti < NW; ti++) {
                const float4 a = *(const float4*)(r1 + 32 * (ti - NW0));
                const float4 b = *(const float4*)(r1 + 32 * (ti - NW0) + 16);
                mreg[8*ti+0] += a.x; mreg[8*ti+1] += a.y;
                mreg[8*ti+2] += a.z; mreg[8*ti+3] += a.w;
                mreg[8*ti+4] += b.x; mreg[8*ti+5] += b.y;
                mreg[8*ti+6] += b.z; mreg[8*ti+7] += b.w;
            }
        }
    }

    float acc[4][8];
#pragma unroll
    for (int r = 0; r < 4; r++)
#pragma unroll
        for (int c = 0; c < 8; c++) acc[r][c] = 0.f;

    for (int ti = 0; ti < 2 * NW; ti++) {
        const int k0 = ti * KT;
        // stage A: msg tiles from mreg; root tiles from own row
        {
            float4 v0, v1;
            if (ti < NW) {
                v0 = make_float4(mreg[8*ti+0], mreg[8*ti+1], mreg[8*ti+2], mreg[8*ti+3]);
                v1 = make_float4(mreg[8*ti+4], mreg[8*ti+5], mreg[8*ti+6], mreg[8*ti+7]);
            } else {
                v0 = make_float4(0.f, 0.f, 0.f, 0.f);
                v1 = v0;
                if (anode >= 0) {
                    const int e = k0 - CIN + 4 * aq;
                    const float* r = (C1 == 0 || e < C0)
                                         ? hin0 + (size_t)anode * C0 + e
                                         : hin1 + (size_t)anode * C1 + (e - C0);
                    v0 = *(const float4*)r;
                    v1 = *(const float4*)(r + 16);
                }
            }
            const int kk0 = 4 * aq, kk1 = kk0 + 16;
            As[kk0 + 0][am] = v0.x; As[kk0 + 1][am] = v0.y;
            As[kk0 + 2][am] = v0.z; As[kk0 + 3][am] = v0.w;
            As[kk1 + 0][am] = v1.x; As[kk1 + 1][am] = v1.y;
            As[kk1 + 2][am] = v1.z; As[kk1 + 3][am] = v1.w;
        }
        // stage B (weights)
#pragma unroll
        for (int j = 0; j < 4; j++) {
            int kk = bk + 8 * j;
            int gk = k0 + kk;
            const float* p = (gk < CIN) ? (WlB + (size_t)gk * COUT + n0 + bn)
                                        : (WrB + (size_t)(gk - CIN) * COUT + n0 + bn);
            *(float4*)&Bs[kk][bn] = *(const float4*)p;
        }
        __syncthreads();
#pragma unroll
        for (int k = 0; k < KT; k++) {
            const float4 a  = *(const float4*)&As[k][ty * 4];
            const float4 b0 = *(const float4*)&Bs[k][4 * tx];        // chunk 0
            const float4 b1 = *(const float4*)&Bs[k][64 + 4 * tx];   // chunk 1
            const float av[4] = {a.x, a.y, a.z, a.w};
            const float bv[8] = {b0.x, b0.y, b0.z, b0.w, b1.x, b1.y, b1.z, b1.w};
#pragma unroll
            for (int r = 0; r < 4; r++)
#pragma unroll
                for (int c = 0; c < 8; c++) acc[r][c] = fmaf(av[r], bv[c], acc[r][c]);
        }
        __syncthreads();
    }

    // epilogue: lane cols are n0 + {4tx..4tx+3} (c<4) and n0+64+{4tx..} (c>=4)
    float blv[8], w0[8], w1[8];
#pragma unroll
    for (int c = 0; c < 8; c++) {
        const int n = n0 + ((c < 4) ? (4 * tx + c) : (64 + 4 * tx + c - 4));
        blv[c] = bl[d * COUT + n];
        w0[c]  = Wf[(size_t)(wf_off + n) * 2 + 0];
        w1[c]  = Wf[(size_t)(wf_off + n) * 2 + 1];
    }
#pragma unroll
    for (int r = 0; r < 4; r++) {
        const int node = rowid[ty * 4 + r];
        float p0 = 0.f, p1 = 0.f;
        if (node >= 0) {
            float h[8];
#pragma unroll
            for (int c = 0; c < 8; c++) {
                h[c] = acc[r][c] + blv[c];
                p0 = fmaf(h[c], w0[c], p0);
                p1 = fmaf(h[c], w1[c], p1);
            }
            if constexpr (POOL_FUSE) {
                float* pr = pool + (size_t)batch[node] * 256 + n0;
#pragma unroll
                for (int c = 0; c < 8; c++) {
                    const int n = (c < 4) ? (4 * tx + c) : (64 + 4 * tx + c - 4);
                    atomicAdd(&pr[n], h[c]);
                }
            } else {
                float* orow = out0 + (size_t)node * COUT + n0;
                *(float4*)(orow + 4 * tx)      = make_float4(h[0], h[1], h[2], h[3]);
                *(float4*)(orow + 64 + 4 * tx) = make_float4(h[4], h[5], h[6], h[7]);
            }
        }
#pragma unroll
        for (int s = 1; s < 16; s <<= 1) {
            p0 += __shfl_xor(p0, s, 64);
            p1 += __shfl_xor(p1, s, 64);
        }
        if (node >= 0 && tx == 0) {
            atomicAdd(&logits[(size_t)node * 2 + 0], p0);
            atomicAdd(&logits[(size_t)node * 2 + 1], p1);
        }
    }
}

// ---------------- layer-2b: full-width GEMM, in-place output ----------------

// h2 = [m2 | h1] @ [Wl; Wr] + bl, d-bucketed; K2 = 256, COUT = 256.
// ONE block owns 64 rows end-to-end (race-free in-place).  Lane cols are four
// chunks {4tx, 64+4tx, 128+4tx, 192+4tx} (2-way LDS bank pattern).
__launch_bounds__(256, 3)
__global__ void k_gemm2b(float* __restrict__ buf0, float* __restrict__ buf1,
                         const float* __restrict__ Wl, const float* __restrict__ bl,
                         const float* __restrict__ Wr, const float* __restrict__ Wf,
                         const int* __restrict__ perm, const int* __restrict__ deg,
                         float* __restrict__ logits) {
    constexpr int K2 = 256, COUT = 256;
    __shared__ float As[KT][BM];     // 8 KB
    __shared__ float Bs[KT][COUT];   // 32 KB
    __shared__ int rowid[BM];

    const int t  = threadIdx.x;
    const int m0 = blockIdx.x * BM;

    if (t < BM) rowid[t] = perm[m0 + t];
    __syncthreads();
    if (rowid[0] < 0) return;

    const int d = min(deg[rowid[0]], MAXD);
    const float* WlB = Wl + (size_t)d * 128 * COUT;
    const float* WrB = Wr + (size_t)d * 128 * COUT;

    const int am = t & 63, aq = t >> 6;
    const int anode = rowid[am];
    const int bn = (t & 63) * 4, bk = t >> 6;
    const int tx = t & 15, ty = t >> 4;

    float acc[4][16];
#pragma unroll
    for (int r = 0; r < 4; r++)
#pragma unroll
        for (int c = 0; c < 16; c++) acc[r][c] = 0.f;

    for (int k0 = 0; k0 < K2; k0 += KT) {
        {
            const int gk0 = k0 + 4 * aq;
            float4 v0 = make_float4(0.f, 0.f, 0.f, 0.f);
            float4 v1 = v0;
            if (anode >= 0) {
                const float* r = (gk0 < 128) ? buf0 + (size_t)anode * 128 + gk0
                                             : buf1 + (size_t)anode * 128 + (gk0 - 128);
                v0 = *(const float4*)r;
                v1 = *(const float4*)(r + 16);
            }
            const int kk0 = 4 * aq, kk1 = kk0 + 16;
            As[kk0 + 0][am] = v0.x; As[kk0 + 1][am] = v0.y;
            As[kk0 + 2][am] = v0.z; As[kk0 + 3][am] = v0.w;
            As[kk1 + 0][am] = v1.x; As[kk1 + 1][am] = v1.y;
            As[kk1 + 2][am] = v1.z; As[kk1 + 3][am] = v1.w;
        }
#pragma unroll
        for (int j = 0; j < 8; j++) {
            int kk = bk + 4 * j;
            int gk = k0 + kk;
            const float* p = (gk < 128) ? (WlB + (size_t)gk * COUT + bn)
                                        : (WrB + (size_t)(gk - 128) * COUT + bn);
            *(float4*)&Bs[kk][bn] = *(const float4*)p;
        }
        __syncthreads();
#pragma unroll
        for (int k = 0; k < KT; k++) {
            const float4 a = *(const float4*)&As[k][ty * 4];
            const float av[4] = {a.x, a.y, a.z, a.w};
            float bv[16];
#pragma unroll
            for (int q = 0; q < 4; q++) {
                const float4 b = *(const float4*)&Bs[k][64 * q + 4 * tx];
                bv[4 * q + 0] = b.x; bv[4 * q + 1] = b.y;
                bv[4 * q + 2] = b.z; bv[4 * q + 3] = b.w;
            }
#pragma unroll
            for (int r = 0; r < 4; r++)
#pragma unroll
                for (int c = 0; c < 16; c++) acc[r][c] = fmaf(av[r], bv[c], acc[r][c]);
        }
        __syncthreads();
    }

    // epilogue: n = 64*(c>>2) + 4*tx + (c&3); q<2 -> buf0, q>=2 -> buf1
    float blv[16], w0[16], w1[16];
#pragma unroll
    for (int c = 0; c < 16; c++) {
        const int n = 64 * (c >> 2) + 4 * tx + (c & 3);
        blv[c] = bl[d * COUT + n];
        w0[c]  = Wf[(size_t)(256 + n) * 2 + 0];
        w1[c]  = Wf[(size_t)(256 + n) * 2 + 1];
    }
#pragma unroll
    for (int r = 0; r < 4; r++) {
        const int node = rowid[ty * 4 + r];
        float p0 = 0.f, p1 = 0.f;
        if (node >= 0) {
            float h[16];
#pragma unroll
            for (int c = 0; c < 16; c++) {
                h[c] = acc[r][c] + blv[c];
                p0 = fmaf(h[c], w0[c], p0);
                p1 = fmaf(h[c], w1[c], p1);
            }
#pragma unroll
            for (int q = 0; q < 4; q++) {
                float* ob = (q < 2) ? buf0 + (size_t)node * 128 + 64 * q + 4 * tx
                                    : buf1 + (size_t)node * 128 + 64 * (q - 2) + 4 * tx;
                *(float4*)ob = make_float4(h[4*q], h[4*q+1], h[4*q+2], h[4*q+3]);
            }
        }
#pragma unroll
        for (int s = 1; s < 16; s <<= 1) {
            p0 += __shfl_xor(p0, s, 64);
            p1 += __shfl_xor(p1, s, 64);
        }
        if (node >= 0 && tx == 0) {
            atomicAdd(&logits[(size_t)node * 2 + 0], p0);
            atomicAdd(&logits[(size_t)node * 2 + 1], p1);
        }
    }
}

// ---------------- pooling / output ----------------

__global__ void k_pool_logits(const float* __restrict__ pool, const float* __restrict__ Wf,
                              const float* __restrict__ bf, float* __restrict__ pl) {
    int g = blockIdx.x * 4 + (threadIdx.x >> 6);
    int lane = threadIdx.x & 63;
    const float* pr = pool + (size_t)g * 256;
    float p0 = 0.f, p1 = 0.f;
#pragma unroll
    for (int j = 0; j < 4; j++) {
        int k = lane + 64 * j;
        float v = pr[k];
        p0 = fmaf(v, Wf[(size_t)(768 + k) * 2 + 0], p0);
        p1 = fmaf(v, Wf[(size_t)(768 + k) * 2 + 1], p1);
    }
#pragma unroll
    for (int s = 1; s < 64; s <<= 1) {
        p0 += __shfl_xor(p0, s, 64);
        p1 += __shfl_xor(p1, s, 64);
    }
    if (lane == 0) {
        pl[(size_t)g * 2 + 0] = p0 + bf[0];
        pl[(size_t)g * 2 + 1] = p1 + bf[1];
    }
}

__global__ void k_final(const float* __restrict__ logits, const float* __restrict__ pl,
                        const int* __restrict__ batch, float* __restrict__ outp) {
    int i = blockIdx.x * 256 + threadIdx.x;
    if (i < NN) {
        int g = batch[i];
        float l0 = logits[(size_t)i * 2 + 0] + pl[(size_t)g * 2 + 0];
        float l1 = logits[(size_t)i * 2 + 1] + pl[(size_t)g * 2 + 1];
        float m = fmaxf(l0, l1);
        float e0 = expf(l0 - m), e1 = expf(l1 - m);
        float inv = 1.f / (e0 + e1);
        outp[(size_t)i * 2 + 0] = e0 * inv;
        outp[(size_t)i * 2 + 1] = e1 * inv;
    }
}

}  // namespace

extern "C" void kernel_launch(void* const* d_in, const int* in_sizes, int n_in,
                              void* d_out, int out_size, void* d_ws, size_t ws_size,
                              hipStream_t stream) {
    const float* x     = (const float*)d_in[0];
    const int*   ei    = (const int*)d_in[1];
    const int*   batch = (const int*)d_in[2];
    const float* Wl0 = (const float*)d_in[3];  const float* bl0 = (const float*)d_in[4];
    const float* Wr0 = (const float*)d_in[5];
    const float* Wl1 = (const float*)d_in[6];  const float* bl1 = (const float*)d_in[7];
    const float* Wr1 = (const float*)d_in[8];
    const float* Wl2 = (const float*)d_in[9];  const float* bl2 = (const float*)d_in[10];
    const float* Wr2 = (const float*)d_in[11];
    const float* Wl3 = (const float*)d_in[12]; const float* bl3 = (const float*)d_in[13];
    const float* Wr3 = (const float*)d_in[14];
    const float* Wf  = (const float*)d_in[15]; const float* bf  = (const float*)d_in[16];
    const int* src = ei;
    const int* dst = ei + NE;
    float* outp = (float*)d_out;
    (void)in_sizes; (void)n_in;

    // workspace bump allocator (256B aligned).  Total ≈ 218 MB (ws is 256 MB).
    char* w = (char*)d_ws;
    auto alloc = [&](size_t bytes) -> void* {
        void* p = (void*)w;
        w += (bytes + 255) & ~(size_t)255;
        return p;
    };
    // zero-init region (contiguous): deg .. pool
    int*   deg    = (int*)alloc((size_t)NN * 4);
    int*   bcnt   = (int*)alloc(32);
    int*   bcur   = (int*)alloc(32);
    float* logits = (float*)alloc((size_t)NN * 2 * 4);
    float* pool   = (float*)alloc((size_t)NG * 256 * 4);
    size_t zero_words = (size_t)(w - (char*)deg) / 4;
    // fully-written-by-kernel regions
    int*   bpad    = (int*)alloc(32);
    int*   perm    = (int*)alloc((size_t)PERMN * 4);      // filled with -1
    int*   row_ptr = (int*)alloc((size_t)(NN + 1) * 4);
    int*   cursor  = (int*)alloc((size_t)NN * 4);
    int*   col     = (int*)alloc((size_t)NE * 4);
    int*   part    = (int*)alloc(1024 * 4);
    float* pl      = (float*)alloc((size_t)NG * 2 * 4);
    float* bufA    = (float*)alloc((size_t)NN * 128 * 4);  // h0 -> m2 -> h2[:,0:128)
    float* bufB    = (float*)alloc((size_t)NN * 128 * 4);  // h1 -> h2[:,128:256)

    size_t required = (size_t)(w - (char*)d_ws);
    if (required > ws_size) {
        k_report<<<(out_size + 255) / 256, 256, 0, stream>>>(
            outp, (float)(double)(ws_size >> 20), out_size);
        return;
    }

    dim3 b256(256);
    k_memset32<<<(int)((zero_words + 255) / 256), b256, 0, stream>>>((int*)deg, 0, (int)zero_words);
    k_memset32<<<(PERMN + 255) / 256, b256, 0, stream>>>(perm, -1, PERMN);

    k_count_deg<<<NE / 256, b256, 0, stream>>>(dst, deg);
    k_scan_part<<<782, b256, 0, stream>>>(deg, part);
    k_scan_single<<<1, 1024, 0, stream>>>(part, 782);
    k_scan_final<<<782, b256, 0, stream>>>(deg, part, row_ptr, cursor);
    k_fill_csr<<<NE / 256, b256, 0, stream>>>(src, dst, cursor, col);
    k_bucket_count<<<782, b256, 0, stream>>>(deg, bcnt);
    k_bucket_scan<<<1, 64, 0, stream>>>(bcnt, bpad);
    k_scatter<<<782, b256, 0, stream>>>(deg, bpad, bcur, perm);

    // Layer 0: in=x(64) -> h0=bufA(128)
    k_transform<64, 0, 128, false><<<dim3(NBLK, 1), b256, 0, stream>>>(
        x, nullptr, row_ptr, col, Wl0, bl0, Wr0, Wf, perm, deg, nullptr,
        bufA, nullptr, logits, 0);
    // Layer 1: in=bufA(128) -> h1=bufB(128)          [h0 dead after this]
    k_transform<128, 0, 128, false><<<dim3(NBLK, 1), b256, 0, stream>>>(
        bufA, nullptr, row_ptr, col, Wl1, bl1, Wr1, Wf, perm, deg, nullptr,
        bufB, nullptr, logits, 128);
    // Layer 2a: m2 = gather-sum(h1) -> bufA
    k_aggregate128<<<NN / 4, b256, 0, stream>>>(bufB, row_ptr, col, bufA);
    // Layer 2b: h2 = [m2|h1] @ [Wl2;Wr2] + bl2, in place -> [bufA|bufB]
    k_gemm2b<<<dim3(NBLK), b256, 0, stream>>>(
        bufA, bufB, Wl2, bl2, Wr2, Wf, perm, deg, logits);
    // Layer 3: in=[bufA|bufB](256) -> logits chunk + pool (h3 never stored)
    k_transform<128, 128, 256, true><<<dim3(NBLK, 2), b256, 0, stream>>>(
        bufA, bufB, row_ptr, col, Wl3, bl3, Wr3, Wf, perm, deg, batch,
        nullptr, pool, logits, 512);

    k_pool_logits<<<NG / 4, b256, 0, stream>>>(pool, Wf, bf, pl);
    k_final<<<782, b256, 0, stream>>>(logits, pl, batch, outp);
}

// Round 8
// 5134.071 us; speedup vs baseline: 1.0315x; 1.0315x over previous
//
#include <hip/hip_runtime.h>
#include <cstdint>
#include <cstddef>

namespace {

constexpr int NN   = 200000;   // nodes
constexpr int NE   = 800000;   // edges
constexpr int NG   = 4096;     // graphs
constexpr int MAXD = 5;

constexpr int BM = 64;
constexpr int BN = 128;
constexpr int KT = 32;
constexpr int NBLK  = (NN + BM - 1) / BM + 6;   // 3125 + 6 = 3131 (bucket padding)
constexpr int PERMN = NBLK * BM;                // 200384

// ---------------- init / diagnostic ----------------

__global__ void k_memset32(int* __restrict__ p, int v, int n) {
    int i = blockIdx.x * 256 + threadIdx.x;
    if (i < n) p[i] = v;
}

__global__ void k_report(float* __restrict__ outp, float v, int n) {
    int i = blockIdx.x * 256 + threadIdx.x;
    if (i < n) outp[i] = v;
}

// ---------------- graph preprocessing ----------------

__global__ void k_count_deg(const int* __restrict__ dst, int* __restrict__ deg) {
    int e = blockIdx.x * 256 + threadIdx.x;
    if (e < NE) atomicAdd(&deg[dst[e]], 1);
}

__global__ void k_scan_part(const int* __restrict__ deg, int* __restrict__ part) {
    __shared__ int s[256];
    int t = threadIdx.x, i = blockIdx.x * 256 + t;
    s[t] = (i < NN) ? deg[i] : 0;
    __syncthreads();
    for (int st = 128; st > 0; st >>= 1) {
        if (t < st) s[t] += s[t + st];
        __syncthreads();
    }
    if (t == 0) part[blockIdx.x] = s[0];
}

__global__ void k_scan_single(int* __restrict__ part, int nb) {
    __shared__ int s[1024];
    int t = threadIdx.x;
    int v0 = (t < nb) ? part[t] : 0;
    s[t] = v0;
    __syncthreads();
    for (int off = 1; off < 1024; off <<= 1) {
        int v = (t >= off) ? s[t - off] : 0;
        __syncthreads();
        s[t] += v;
        __syncthreads();
    }
    if (t < nb) part[t] = s[t] - v0;   // exclusive prefix of block sums
}

__global__ void k_scan_final(const int* __restrict__ deg, const int* __restrict__ part,
                             int* __restrict__ row_ptr, int* __restrict__ cursor) {
    __shared__ int s[256];
    int t = threadIdx.x, i = blockIdx.x * 256 + t;
    int v0 = (i < NN) ? deg[i] : 0;
    s[t] = v0;
    __syncthreads();
    for (int off = 1; off < 256; off <<= 1) {
        int v = (t >= off) ? s[t - off] : 0;
        __syncthreads();
        s[t] += v;
        __syncthreads();
    }
    if (i < NN) {
        int excl = s[t] - v0 + part[blockIdx.x];
        row_ptr[i] = excl;
        cursor[i]  = excl;
        if (i == NN - 1) row_ptr[NN] = excl + v0;
    }
}

__global__ void k_fill_csr(const int* __restrict__ src, const int* __restrict__ dst,
                           int* __restrict__ cursor, int* __restrict__ col) {
    int e = blockIdx.x * 256 + threadIdx.x;
    if (e < NE) {
        int d = dst[e];
        int slot = atomicAdd(&cursor[d], 1);
        col[slot] = src[e];
    }
}

__global__ void k_bucket_count(const int* __restrict__ deg, int* __restrict__ bcnt) {
    int i = blockIdx.x * 256 + threadIdx.x;
    if (i < NN) atomicAdd(&bcnt[min(deg[i], MAXD)], 1);
}

__global__ void k_bucket_scan(const int* __restrict__ bcnt, int* __restrict__ bpad) {
    if (threadIdx.x == 0 && blockIdx.x == 0) {
        int off = 0;
        for (int b = 0; b < 6; b++) {
            bpad[b] = off;
            off += ((bcnt[b] + BM - 1) / BM) * BM;
        }
        bpad[6] = off;
    }
}

__global__ void k_scatter(const int* __restrict__ deg, const int* __restrict__ bpad,
                          int* __restrict__ bcur, int* __restrict__ perm) {
    int i = blockIdx.x * 256 + threadIdx.x;
    if (i < NN) {
        int b = min(deg[i], MAXD);
        int pos = atomicAdd(&bcur[b], 1);
        perm[bpad[b] + pos] = i;
    }
}

// ---------------- layer-2a: plain neighbor-sum aggregate ----------------

__global__ void k_aggregate128(const float* __restrict__ hin, const int* __restrict__ row_ptr,
                               const int* __restrict__ col, float* __restrict__ msg) {
    int node = blockIdx.x * 4 + (threadIdx.x >> 6);
    int lane = threadIdx.x & 63;
    int s = row_ptr[node], e = row_ptr[node + 1];
    float2 acc = make_float2(0.f, 0.f);
    for (int p = s; p < e; p++) {
        const float2 v = *(const float2*)(hin + (size_t)col[p] * 128 + lane * 2);
        acc.x += v.x; acc.y += v.y;
    }
    *(float2*)(msg + (size_t)node * 128 + lane * 2) = acc;
}

// ---------------- fused aggregate + transform (prefetch pipeline) ----------------

// out[i] = [sum_{j->i} hin[j], hin[i]] @ [Wl[d]; Wr[d]] + bl[d], d = bucket(i).
// Per K-tile, the NEXT tile's A-fragment (8 floats, constant-indexed scalars —
// never scratch, unlike round-6/7's runtime-indexed mreg[]) is gathered between
// the barriers while the current tile's 1024 FMAs execute: global-load latency
// overlaps compute within the wave + across ~5 waves/EU.
// Lane B-columns are two chunks {4tx, 64+4tx} (2-way LDS bank pattern = free).
// POOL_FUSE: no h store; rows atomically accumulated into pool[batch[node]].
// Epilogue always banks this chunk's Wf contribution into per-node logits.
template <int C0, int C1, int COUT, bool POOL_FUSE>
__launch_bounds__(256, 4)
__global__ void k_transform(const float* __restrict__ hin0, const float* __restrict__ hin1,
                            const int* __restrict__ row_ptr, const int* __restrict__ col,
                            const float* __restrict__ Wl, const float* __restrict__ bl,
                            const float* __restrict__ Wr, const float* __restrict__ Wf,
                            const int* __restrict__ perm, const int* __restrict__ deg,
                            const int* __restrict__ batch,
                            float* __restrict__ out0, float* __restrict__ pool,
                            float* __restrict__ logits, int wf_off) {
    constexpr int CIN = C0 + C1;
    constexpr int NW0 = C0 / 32;    // msg windows served by hin0
    constexpr int NW  = CIN / 32;   // msg windows total
    constexpr int NT  = 2 * NW;     // total K-tiles
    __shared__ float As[KT][BM];
    __shared__ float Bs[KT][BN];
    __shared__ int rowid[BM];

    const int t  = threadIdx.x;
    const int m0 = blockIdx.x * BM;
    const int n0 = blockIdx.y * BN;

    if (t < BM) rowid[t] = perm[m0 + t];
    __syncthreads();
    if (rowid[0] < 0) return;  // fully-padded block (uniform exit)

    const int d = min(deg[rowid[0]], MAXD);
    const float* WlB = Wl + (size_t)d * CIN * COUT;
    const float* WrB = Wr + (size_t)d * CIN * COUT;

    const int am = t & 63, aq = t >> 6;
    const int anode = rowid[am];
    int es = 0, ee = 0;
    if (anode >= 0) { es = row_ptr[anode]; ee = row_ptr[anode + 1]; }
    const int bn = (t & 31) * 4, bk = t >> 5;
    const int tx = t & 15, ty = t >> 4;

    // gather A-fragment for tile ti into g[8] (scalars, constant indices)
    auto gather = [&](int ti, float* g) {
#pragma unroll
        for (int i = 0; i < 8; i++) g[i] = 0.f;
        if (ti < NW) {  // msg half: sum neighbor slices
            const bool lo = (C1 == 0) || (ti < NW0);
            const float* base = lo ? hin0 : hin1;
            const int stride  = lo ? C0 : C1;
            const int off     = (lo ? 32 * ti : 32 * (ti - NW0)) + 4 * aq;
            for (int p = es; p < ee; p++) {
                const float* r = base + (size_t)col[p] * stride + off;
                const float4 a = *(const float4*)r;
                const float4 b = *(const float4*)(r + 16);
                g[0] += a.x; g[1] += a.y; g[2] += a.z; g[3] += a.w;
                g[4] += b.x; g[5] += b.y; g[6] += b.z; g[7] += b.w;
            }
        } else if (anode >= 0) {  // root half: own row
            const int e = (ti - NW) * 32 + 4 * aq;
            const float* r = (C1 == 0 || e < C0)
                                 ? hin0 + (size_t)anode * C0 + e
                                 : hin1 + (size_t)anode * C1 + (e - C0);
            const float4 a = *(const float4*)r;
            const float4 b = *(const float4*)(r + 16);
            g[0] = a.x; g[1] = a.y; g[2] = a.z; g[3] = a.w;
            g[4] = b.x; g[5] = b.y; g[6] = b.z; g[7] = b.w;
        }
    };

    float acc[4][8];
#pragma unroll
    for (int r = 0; r < 4; r++)
#pragma unroll
        for (int c = 0; c < 8; c++) acc[r][c] = 0.f;

    float gcur[8];
    gather(0, gcur);

    for (int ti = 0; ti < NT; ti++) {
        // stage A from the prefetched fragment
        {
            const int kk0 = 4 * aq, kk1 = kk0 + 16;
            As[kk0 + 0][am] = gcur[0]; As[kk0 + 1][am] = gcur[1];
            As[kk0 + 2][am] = gcur[2]; As[kk0 + 3][am] = gcur[3];
            As[kk1 + 0][am] = gcur[4]; As[kk1 + 1][am] = gcur[5];
            As[kk1 + 2][am] = gcur[6]; As[kk1 + 3][am] = gcur[7];
        }
        // stage B (weights)
        const int k0 = ti * KT;
#pragma unroll
        for (int j = 0; j < 4; j++) {
            int kk = bk + 8 * j;
            int gk = k0 + kk;
            const float* p = (gk < CIN) ? (WlB + (size_t)gk * COUT + n0 + bn)
                                        : (WrB + (size_t)(gk - CIN) * COUT + n0 + bn);
            *(float4*)&Bs[kk][bn] = *(const float4*)p;
        }
        __syncthreads();

        // prefetch next tile's fragment (overlaps the FMA block below)
        float gnext[8];
        if (ti + 1 < NT) {
            gather(ti + 1, gnext);
        } else {
#pragma unroll
            for (int i = 0; i < 8; i++) gnext[i] = 0.f;
        }

        // FMA over tile ti
#pragma unroll
        for (int k = 0; k < KT; k++) {
            const float4 a  = *(const float4*)&As[k][ty * 4];
            const float4 b0 = *(const float4*)&Bs[k][4 * tx];        // chunk 0
            const float4 b1 = *(const float4*)&Bs[k][64 + 4 * tx];   // chunk 1
            const float av[4] = {a.x, a.y, a.z, a.w};
            const float bv[8] = {b0.x, b0.y, b0.z, b0.w, b1.x, b1.y, b1.z, b1.w};
#pragma unroll
            for (int r = 0; r < 4; r++)
#pragma unroll
                for (int c = 0; c < 8; c++) acc[r][c] = fmaf(av[r], bv[c], acc[r][c]);
        }
        __syncthreads();

#pragma unroll
        for (int i = 0; i < 8; i++) gcur[i] = gnext[i];
    }

    // epilogue: lane cols are n0 + {4tx..4tx+3} (c<4) and n0+64+{4tx..} (c>=4)
    float blv[8], w0[8], w1[8];
#pragma unroll
    for (int c = 0; c < 8; c++) {
        const int n = n0 + ((c < 4) ? (4 * tx + c) : (64 + 4 * tx + c - 4));
        blv[c] = bl[d * COUT + n];
        w0[c]  = Wf[(size_t)(wf_off + n) * 2 + 0];
        w1[c]  = Wf[(size_t)(wf_off + n) * 2 + 1];
    }
#pragma unroll
    for (int r = 0; r < 4; r++) {
        const int node = rowid[ty * 4 + r];
        float p0 = 0.f, p1 = 0.f;
        if (node >= 0) {
            float h[8];
#pragma unroll
            for (int c = 0; c < 8; c++) {
                h[c] = acc[r][c] + blv[c];
                p0 = fmaf(h[c], w0[c], p0);
                p1 = fmaf(h[c], w1[c], p1);
            }
            if constexpr (POOL_FUSE) {
                float* pr = pool + (size_t)batch[node] * 256 + n0;
#pragma unroll
                for (int c = 0; c < 8; c++) {
                    const int n = (c < 4) ? (4 * tx + c) : (64 + 4 * tx + c - 4);
                    atomicAdd(&pr[n], h[c]);
                }
            } else {
                float* orow = out0 + (size_t)node * COUT + n0;
                *(float4*)(orow + 4 * tx)      = make_float4(h[0], h[1], h[2], h[3]);
                *(float4*)(orow + 64 + 4 * tx) = make_float4(h[4], h[5], h[6], h[7]);
            }
        }
#pragma unroll
        for (int s = 1; s < 16; s <<= 1) {
            p0 += __shfl_xor(p0, s, 64);
            p1 += __shfl_xor(p1, s, 64);
        }
        if (node >= 0 && tx == 0) {
            atomicAdd(&logits[(size_t)node * 2 + 0], p0);
            atomicAdd(&logits[(size_t)node * 2 + 1], p1);
        }
    }
}

// ---------------- layer-2b: full-width GEMM, in-place output ----------------

// h2 = [m2 | h1] @ [Wl; Wr] + bl, d-bucketed; K2 = 256, COUT = 256.
// ONE block owns 64 rows end-to-end (race-free in-place).  Lane cols are four
// chunks {4tx, 64+4tx, 128+4tx, 192+4tx} (2-way LDS bank pattern).
// LDS 41 KB caps at 3 blocks/CU; (256,3) gives a ~170-VGPR budget (no spill).
__launch_bounds__(256, 3)
__global__ void k_gemm2b(float* __restrict__ buf0, float* __restrict__ buf1,
                         const float* __restrict__ Wl, const float* __restrict__ bl,
                         const float* __restrict__ Wr, const float* __restrict__ Wf,
                         const int* __restrict__ perm, const int* __restrict__ deg,
                         float* __restrict__ logits) {
    constexpr int K2 = 256, COUT = 256;
    __shared__ float As[KT][BM];     // 8 KB
    __shared__ float Bs[KT][COUT];   // 32 KB
    __shared__ int rowid[BM];

    const int t  = threadIdx.x;
    const int m0 = blockIdx.x * BM;

    if (t < BM) rowid[t] = perm[m0 + t];
    __syncthreads();
    if (rowid[0] < 0) return;

    const int d = min(deg[rowid[0]], MAXD);
    const float* WlB = Wl + (size_t)d * 128 * COUT;
    const float* WrB = Wr + (size_t)d * 128 * COUT;

    const int am = t & 63, aq = t >> 6;
    const int anode = rowid[am];
    const int bn = (t & 63) * 4, bk = t >> 6;
    const int tx = t & 15, ty = t >> 4;

    float acc[4][16];
#pragma unroll
    for (int r = 0; r < 4; r++)
#pragma unroll
        for (int c = 0; c < 16; c++) acc[r][c] = 0.f;

    for (int k0 = 0; k0 < K2; k0 += KT) {
        {
            const int gk0 = k0 + 4 * aq;
            float4 v0 = make_float4(0.f, 0.f, 0.f, 0.f);
            float4 v1 = v0;
            if (anode >= 0) {
                const float* r = (gk0 < 128) ? buf0 + (size_t)anode * 128 + gk0
                                             : buf1 + (size_t)anode * 128 + (gk0 - 128);
                v0 = *(const float4*)r;
                v1 = *(const float4*)(r + 16);
            }
            const int kk0 = 4 * aq, kk1 = kk0 + 16;
            As[kk0 + 0][am] = v0.x; As[kk0 + 1][am] = v0.y;
            As[kk0 + 2][am] = v0.z; As[kk0 + 3][am] = v0.w;
            As[kk1 + 0][am] = v1.x; As[kk1 + 1][am] = v1.y;
            As[kk1 + 2][am] = v1.z; As[kk1 + 3][am] = v1.w;
        }
#pragma unroll
        for (int j = 0; j < 8; j++) {
            int kk = bk + 4 * j;
            int gk = k0 + kk;
            const float* p = (gk < 128) ? (WlB + (size_t)gk * COUT + bn)
                                        : (WrB + (size_t)(gk - 128) * COUT + bn);
            *(float4*)&Bs[kk][bn] = *(const float4*)p;
        }
        __syncthreads();
#pragma unroll
        for (int k = 0; k < KT; k++) {
            const float4 a = *(const float4*)&As[k][ty * 4];
            const float av[4] = {a.x, a.y, a.z, a.w};
            float bv[16];
#pragma unroll
            for (int q = 0; q < 4; q++) {
                const float4 b = *(const float4*)&Bs[k][64 * q + 4 * tx];
                bv[4 * q + 0] = b.x; bv[4 * q + 1] = b.y;
                bv[4 * q + 2] = b.z; bv[4 * q + 3] = b.w;
            }
#pragma unroll
            for (int r = 0; r < 4; r++)
#pragma unroll
                for (int c = 0; c < 16; c++) acc[r][c] = fmaf(av[r], bv[c], acc[r][c]);
        }
        __syncthreads();
    }

    // epilogue: n = 64*(c>>2) + 4*tx + (c&3); q<2 -> buf0, q>=2 -> buf1
    float blv[16], w0[16], w1[16];
#pragma unroll
    for (int c = 0; c < 16; c++) {
        const int n = 64 * (c >> 2) + 4 * tx + (c & 3);
        blv[c] = bl[d * COUT + n];
        w0[c]  = Wf[(size_t)(256 + n) * 2 + 0];
        w1[c]  = Wf[(size_t)(256 + n) * 2 + 1];
    }
#pragma unroll
    for (int r = 0; r < 4; r++) {
        const int node = rowid[ty * 4 + r];
        float p0 = 0.f, p1 = 0.f;
        if (node >= 0) {
            float h[16];
#pragma unroll
            for (int c = 0; c < 16; c++) {
                h[c] = acc[r][c] + blv[c];
                p0 = fmaf(h[c], w0[c], p0);
                p1 = fmaf(h[c], w1[c], p1);
            }
#pragma unroll
            for (int q = 0; q < 4; q++) {
                float* ob = (q < 2) ? buf0 + (size_t)node * 128 + 64 * q + 4 * tx
                                    : buf1 + (size_t)node * 128 + 64 * (q - 2) + 4 * tx;
                *(float4*)ob = make_float4(h[4*q], h[4*q+1], h[4*q+2], h[4*q+3]);
            }
        }
#pragma unroll
        for (int s = 1; s < 16; s <<= 1) {
            p0 += __shfl_xor(p0, s, 64);
            p1 += __shfl_xor(p1, s, 64);
        }
        if (node >= 0 && tx == 0) {
            atomicAdd(&logits[(size_t)node * 2 + 0], p0);
            atomicAdd(&logits[(size_t)node * 2 + 1], p1);
        }
    }
}

// ---------------- pooling / output ----------------

__global__ void k_pool_logits(const float* __restrict__ pool, const float* __restrict__ Wf,
                              const float* __restrict__ bf, float* __restrict__ pl) {
    int g = blockIdx.x * 4 + (threadIdx.x >> 6);
    int lane = threadIdx.x & 63;
    const float* pr = pool + (size_t)g * 256;
    float p0 = 0.f, p1 = 0.f;
#pragma unroll
    for (int j = 0; j < 4; j++) {
        int k = lane + 64 * j;
        float v = pr[k];
        p0 = fmaf(v, Wf[(size_t)(768 + k) * 2 + 0], p0);
        p1 = fmaf(v, Wf[(size_t)(768 + k) * 2 + 1], p1);
    }
#pragma unroll
    for (int s = 1; s < 64; s <<= 1) {
        p0 += __shfl_xor(p0, s, 64);
        p1 += __shfl_xor(p1, s, 64);
    }
    if (lane == 0) {
        pl[(size_t)g * 2 + 0] = p0 + bf[0];
        pl[(size_t)g * 2 + 1] = p1 + bf[1];
    }
}

__global__ void k_final(const float* __restrict__ logits, const float* __restrict__ pl,
                        const int* __restrict__ batch, float* __restrict__ outp) {
    int i = blockIdx.x * 256 + threadIdx.x;
    if (i < NN) {
        int g = batch[i];
        float l0 = logits[(size_t)i * 2 + 0] + pl[(size_t)g * 2 + 0];
        float l1 = logits[(size_t)i * 2 + 1] + pl[(size_t)g * 2 + 1];
        float m = fmaxf(l0, l1);
        float e0 = expf(l0 - m), e1 = expf(l1 - m);
        float inv = 1.f / (e0 + e1);
        outp[(size_t)i * 2 + 0] = e0 * inv;
        outp[(size_t)i * 2 + 1] = e1 * inv;
    }
}

}  // namespace

extern "C" void kernel_launch(void* const* d_in, const int* in_sizes, int n_in,
                              void* d_out, int out_size, void* d_ws, size_t ws_size,
                              hipStream_t stream) {
    const float* x     = (const float*)d_in[0];
    const int*   ei    = (const int*)d_in[1];
    const int*   batch = (const int*)d_in[2];
    const float* Wl0 = (const float*)d_in[3];  const float* bl0 = (const float*)d_in[4];
    const float* Wr0 = (const float*)d_in[5];
    const float* Wl1 = (const float*)d_in[6];  const float* bl1 = (const float*)d_in[7];
    const float* Wr1 = (const float*)d_in[8];
    const float* Wl2 = (const float*)d_in[9];  const float* bl2 = (const float*)d_in[10];
    const float* Wr2 = (const float*)d_in[11];
    const float* Wl3 = (const float*)d_in[12]; const float* bl3 = (const float*)d_in[13];
    const float* Wr3 = (const float*)d_in[14];
    const float* Wf  = (const float*)d_in[15]; const float* bf  = (const float*)d_in[16];
    const int* src = ei;
    const int* dst = ei + NE;
    float* outp = (float*)d_out;
    (void)in_sizes; (void)n_in;

    // workspace bump allocator (256B aligned).  Total ≈ 218 MB (ws is 256 MB).
    char* w = (char*)d_ws;
    auto alloc = [&](size_t bytes) -> void* {
        void* p = (void*)w;
        w += (bytes + 255) & ~(size_t)255;
        return p;
    };
    // zero-init region (contiguous): deg .. pool
    int*   deg    = (int*)alloc((size_t)NN * 4);
    int*   bcnt   = (int*)alloc(32);
    int*   bcur   = (int*)alloc(32);
    float* logits = (float*)alloc((size_t)NN * 2 * 4);
    float* pool   = (float*)alloc((size_t)NG * 256 * 4);
    size_t zero_words = (size_t)(w - (char*)deg) / 4;
    // fully-written-by-kernel regions
    int*   bpad    = (int*)alloc(32);
    int*   perm    = (int*)alloc((size_t)PERMN * 4);      // filled with -1
    int*   row_ptr = (int*)alloc((size_t)(NN + 1) * 4);
    int*   cursor  = (int*)alloc((size_t)NN * 4);
    int*   col     = (int*)alloc((size_t)NE * 4);
    int*   part    = (int*)alloc(1024 * 4);
    float* pl      = (float*)alloc((size_t)NG * 2 * 4);
    float* bufA    = (float*)alloc((size_t)NN * 128 * 4);  // h0 -> m2 -> h2[:,0:128)
    float* bufB    = (float*)alloc((size_t)NN * 128 * 4);  // h1 -> h2[:,128:256)

    size_t required = (size_t)(w - (char*)d_ws);
    if (required > ws_size) {
        k_report<<<(out_size + 255) / 256, 256, 0, stream>>>(
            outp, (float)(double)(ws_size >> 20), out_size);
        return;
    }

    dim3 b256(256);
    k_memset32<<<(int)((zero_words + 255) / 256), b256, 0, stream>>>((int*)deg, 0, (int)zero_words);
    k_memset32<<<(PERMN + 255) / 256, b256, 0, stream>>>(perm, -1, PERMN);

    k_count_deg<<<NE / 256, b256, 0, stream>>>(dst, deg);
    k_scan_part<<<782, b256, 0, stream>>>(deg, part);
    k_scan_single<<<1, 1024, 0, stream>>>(part, 782);
    k_scan_final<<<782, b256, 0, stream>>>(deg, part, row_ptr, cursor);
    k_fill_csr<<<NE / 256, b256, 0, stream>>>(src, dst, cursor, col);
    k_bucket_count<<<782, b256, 0, stream>>>(deg, bcnt);
    k_bucket_scan<<<1, 64, 0, stream>>>(bcnt, bpad);
    k_scatter<<<782, b256, 0, stream>>>(deg, bpad, bcur, perm);

    // Layer 0: in=x(64) -> h0=bufA(128)
    k_transform<64, 0, 128, false><<<dim3(NBLK, 1), b256, 0, stream>>>(
        x, nullptr, row_ptr, col, Wl0, bl0, Wr0, Wf, perm, deg, nullptr,
        bufA, nullptr, logits, 0);
    // Layer 1: in=bufA(128) -> h1=bufB(128)          [h0 dead after this]
    k_transform<128, 0, 128, false><<<dim3(NBLK, 1), b256, 0, stream>>>(
        bufA, nullptr, row_ptr, col, Wl1, bl1, Wr1, Wf, perm, deg, nullptr,
        bufB, nullptr, logits, 128);
    // Layer 2a: m2 = gather-sum(h1) -> bufA
    k_aggregate128<<<NN / 4, b256, 0, stream>>>(bufB, row_ptr, col, bufA);
    // Layer 2b: h2 = [m2|h1] @ [Wl2;Wr2] + bl2, in place -> [bufA|bufB]
    k_gemm2b<<<dim3(NBLK), b256, 0, stream>>>(
        bufA, bufB, Wl2, bl2, Wr2, Wf, perm, deg, logits);
    // Layer 3: in=[bufA|bufB](256) -> logits chunk + pool (h3 never stored)
    k_transform<128, 128, 256, true><<<dim3(NBLK, 2), b256, 0, stream>>>(
        bufA, bufB, row_ptr, col, Wl3, bl3, Wr3, Wf, perm, deg, batch,
        nullptr, pool, logits, 512);

    k_pool_logits<<<NG / 4, b256, 0, stream>>>(pool, Wf, bf, pl);
    k_final<<<782, b256, 0, stream>>>(logits, pl, batch, outp);
}

// Round 9
// 4316.377 us; speedup vs baseline: 1.2270x; 1.1894x over previous
//
#include <hip/hip_runtime.h>
#include <cstdint>
#include <cstddef>

namespace {

constexpr int NN   = 200000;   // nodes
constexpr int NE   = 800000;   // edges
constexpr int NG   = 4096;     // graphs
constexpr int MAXD = 5;

constexpr int BM = 64;
constexpr int KT = 32;
constexpr int KP = KT + 8;     // padded LDS row (f16), 80 B rows keep 16B align
constexpr int NBLK  = (NN + BM - 1) / BM + 6;   // 3131 (bucket padding)
constexpr int PERMN = NBLK * BM;                // 200384

typedef _Float16 half8 __attribute__((ext_vector_type(8)));
typedef _Float16 half4 __attribute__((ext_vector_type(4)));
typedef float    f32x4 __attribute__((ext_vector_type(4)));

// weight-split buffer element offsets
constexpr size_t S_L0 = (size_t)6 * 64 * 128;    // 49152
constexpr size_t S_L1 = (size_t)6 * 128 * 128;   // 98304
constexpr size_t S_L2 = (size_t)6 * 128 * 256;   // 196608
constexpr size_t S_L3 = (size_t)6 * 256 * 256;   // 393216
constexpr size_t O_WL0 = 0;
constexpr size_t O_WR0 = O_WL0 + S_L0;
constexpr size_t O_WL1 = O_WR0 + S_L0;
constexpr size_t O_WR1 = O_WL1 + S_L1;
constexpr size_t O_WL2 = O_WR1 + S_L1;
constexpr size_t O_WR2 = O_WL2 + S_L2;
constexpr size_t O_WL3 = O_WR2 + S_L2;
constexpr size_t O_WR3 = O_WL3 + S_L3;
constexpr size_t WTOT  = O_WR3 + S_L3;           // 1,474,560 elements

// ---------------- init / diagnostic ----------------

__global__ void k_memset32(int* __restrict__ p, int v, int n) {
    int i = blockIdx.x * 256 + threadIdx.x;
    if (i < n) p[i] = v;
}

__global__ void k_report(float* __restrict__ outp, float v, int n) {
    int i = blockIdx.x * 256 + threadIdx.x;
    if (i < n) outp[i] = v;
}

// fp32 -> f16 hi/lo split (exact: v = hi + lo + O(2^-22 v))
__global__ void k_wsplit(const float* __restrict__ w, _Float16* __restrict__ hi,
                         _Float16* __restrict__ lo, int n) {
    int i = blockIdx.x * 256 + threadIdx.x;
    if (i < n) {
        float v = w[i];
        _Float16 h = (_Float16)v;
        hi[i] = h;
        lo[i] = (_Float16)(v - (float)h);
    }
}

// ---------------- graph preprocessing ----------------

__global__ void k_count_deg(const int* __restrict__ dst, int* __restrict__ deg) {
    int e = blockIdx.x * 256 + threadIdx.x;
    if (e < NE) atomicAdd(&deg[dst[e]], 1);
}

__global__ void k_scan_part(const int* __restrict__ deg, int* __restrict__ part) {
    __shared__ int s[256];
    int t = threadIdx.x, i = blockIdx.x * 256 + t;
    s[t] = (i < NN) ? deg[i] : 0;
    __syncthreads();
    for (int st = 128; st > 0; st >>= 1) {
        if (t < st) s[t] += s[t + st];
        __syncthreads();
    }
    if (t == 0) part[blockIdx.x] = s[0];
}

__global__ void k_scan_single(int* __restrict__ part, int nb) {
    __shared__ int s[1024];
    int t = threadIdx.x;
    int v0 = (t < nb) ? part[t] : 0;
    s[t] = v0;
    __syncthreads();
    for (int off = 1; off < 1024; off <<= 1) {
        int v = (t >= off) ? s[t - off] : 0;
        __syncthreads();
        s[t] += v;
        __syncthreads();
    }
    if (t < nb) part[t] = s[t] - v0;
}

__global__ void k_scan_final(const int* __restrict__ deg, const int* __restrict__ part,
                             int* __restrict__ row_ptr, int* __restrict__ cursor) {
    __shared__ int s[256];
    int t = threadIdx.x, i = blockIdx.x * 256 + t;
    int v0 = (i < NN) ? deg[i] : 0;
    s[t] = v0;
    __syncthreads();
    for (int off = 1; off < 256; off <<= 1) {
        int v = (t >= off) ? s[t - off] : 0;
        __syncthreads();
        s[t] += v;
        __syncthreads();
    }
    if (i < NN) {
        int excl = s[t] - v0 + part[blockIdx.x];
        row_ptr[i] = excl;
        cursor[i]  = excl;
        if (i == NN - 1) row_ptr[NN] = excl + v0;
    }
}

__global__ void k_fill_csr(const int* __restrict__ src, const int* __restrict__ dst,
                           int* __restrict__ cursor, int* __restrict__ col) {
    int e = blockIdx.x * 256 + threadIdx.x;
    if (e < NE) {
        int d = dst[e];
        int slot = atomicAdd(&cursor[d], 1);
        col[slot] = src[e];
    }
}

__global__ void k_bucket_count(const int* __restrict__ deg, int* __restrict__ bcnt) {
    int i = blockIdx.x * 256 + threadIdx.x;
    if (i < NN) atomicAdd(&bcnt[min(deg[i], MAXD)], 1);
}

__global__ void k_bucket_scan(const int* __restrict__ bcnt, int* __restrict__ bpad) {
    if (threadIdx.x == 0 && blockIdx.x == 0) {
        int off = 0;
        for (int b = 0; b < 6; b++) {
            bpad[b] = off;
            off += ((bcnt[b] + BM - 1) / BM) * BM;
        }
        bpad[6] = off;
    }
}

__global__ void k_scatter(const int* __restrict__ deg, const int* __restrict__ bpad,
                          int* __restrict__ bcur, int* __restrict__ perm) {
    int i = blockIdx.x * 256 + threadIdx.x;
    if (i < NN) {
        int b = min(deg[i], MAXD);
        int pos = atomicAdd(&bcur[b], 1);
        perm[bpad[b] + pos] = i;
    }
}

// ---------------- layer-2a: plain neighbor-sum aggregate ----------------

__global__ void k_aggregate128(const float* __restrict__ hin, const int* __restrict__ row_ptr,
                               const int* __restrict__ col, float* __restrict__ msg) {
    int node = blockIdx.x * 4 + (threadIdx.x >> 6);
    int lane = threadIdx.x & 63;
    int s = row_ptr[node], e = row_ptr[node + 1];
    float2 acc = make_float2(0.f, 0.f);
    for (int p = s; p < e; p++) {
        const float2 v = *(const float2*)(hin + (size_t)col[p] * 128 + lane * 2);
        acc.x += v.x; acc.y += v.y;
    }
    *(float2*)(msg + (size_t)node * 128 + lane * 2) = acc;
}

// ---------------- fused aggregate + transform (MFMA f16-split) ----------------

// out[i] = [sum_{j->i} hin[j], hin[i]] @ [Wl[d]; Wr[d]] + bl[d], d = bucket(i).
// Core is mfma_f32_16x16x32_f16, 3-pass f16 hi/lo split (exact to ~2^-22 rel).
// Gather prefetch pipeline (round 8) retained: next tile's 8-float fragment
// gathered while current tile's MFMAs run.  Weights pre-split to f16 hi/lo.
// A/B LDS layout [row][k] f16, row stride KP=40 (16B-aligned, padded).
// POOL_FUSE: no h store; rows atomically accumulated into pool[batch[node]].
// Epilogue banks this chunk's Wf contribution into per-node logits.
template <int C0, int C1, int COUT, int BN_, bool POOL_FUSE>
__launch_bounds__(256, (BN_ == 256) ? 3 : 4)
__global__ void k_transform(const float* __restrict__ hin0, const float* __restrict__ hin1,
                            const int* __restrict__ row_ptr, const int* __restrict__ col,
                            const _Float16* __restrict__ wlh, const _Float16* __restrict__ wll,
                            const _Float16* __restrict__ wrh, const _Float16* __restrict__ wrl,
                            const float* __restrict__ bias, const float* __restrict__ Wf,
                            const int* __restrict__ perm, const int* __restrict__ deg,
                            const int* __restrict__ batch,
                            float* __restrict__ out0, float* __restrict__ pool,
                            float* __restrict__ logits, int wf_off) {
    constexpr int CIN = C0 + C1;
    constexpr int NW0 = C0 / 32;
    constexpr int NW  = CIN / 32;
    constexpr int NT  = 2 * NW;
    constexpr int NTN = BN_ / 64;        // N-tiles per wave (2 or 4)
    constexpr int LPR = BN_ / 4;         // B-staging lanes per k-row
    constexpr int KSTEP = 256 / LPR;     // k-rows per staging pass
    __shared__ _Float16 Ah[BM][KP];
    __shared__ _Float16 Al[BM][KP];
    __shared__ _Float16 Bh[BN_][KP];
    __shared__ _Float16 Blo[BN_][KP];
    __shared__ int rowid[BM];

    const int t  = threadIdx.x;
    const int m0 = blockIdx.x * BM;
    const int n0 = blockIdx.y * BN_;

    if (t < BM) rowid[t] = perm[m0 + t];
    __syncthreads();
    if (rowid[0] < 0) return;  // fully-padded block (uniform exit)

    const int d = min(deg[rowid[0]], MAXD);
    const _Float16* WlhB = wlh + (size_t)d * CIN * COUT;
    const _Float16* WllB = wll + (size_t)d * CIN * COUT;
    const _Float16* WrhB = wrh + (size_t)d * CIN * COUT;
    const _Float16* WrlB = wrl + (size_t)d * CIN * COUT;

    const int am = t & 63, aq = t >> 6;
    const int anode = rowid[am];
    int es = 0, ee = 0;
    if (anode >= 0) { es = row_ptr[anode]; ee = row_ptr[anode + 1]; }
    const int bn = (t % LPR) * 4, bk = t / LPR;
    const int lx = t & 15, qd = (t >> 4) & 3, wv = t >> 6;

    // gather A-fragment for tile ti into g[8] (constant-indexed scalars)
    auto gather = [&](int ti, float* g) {
#pragma unroll
        for (int i = 0; i < 8; i++) g[i] = 0.f;
        if (ti < NW) {
            const bool lo = (C1 == 0) || (ti < NW0);
            const float* base = lo ? hin0 : hin1;
            const int stride  = lo ? C0 : C1;
            const int off     = (lo ? 32 * ti : 32 * (ti - NW0)) + 4 * aq;
            for (int p = es; p < ee; p++) {
                const float* r = base + (size_t)col[p] * stride + off;
                const float4 a = *(const float4*)r;
                const float4 b = *(const float4*)(r + 16);
                g[0] += a.x; g[1] += a.y; g[2] += a.z; g[3] += a.w;
                g[4] += b.x; g[5] += b.y; g[6] += b.z; g[7] += b.w;
            }
        } else if (anode >= 0) {
            const int e = (ti - NW) * 32 + 4 * aq;
            const float* r = (C1 == 0 || e < C0)
                                 ? hin0 + (size_t)anode * C0 + e
                                 : hin1 + (size_t)anode * C1 + (e - C0);
            const float4 a = *(const float4*)r;
            const float4 b = *(const float4*)(r + 16);
            g[0] = a.x; g[1] = a.y; g[2] = a.z; g[3] = a.w;
            g[4] = b.x; g[5] = b.y; g[6] = b.z; g[7] = b.w;
        }
    };

    f32x4 acc[4][NTN];
#pragma unroll
    for (int mt = 0; mt < 4; mt++)
#pragma unroll
        for (int nt = 0; nt < NTN; nt++) acc[mt][nt] = (f32x4)0.f;

    float gcur[8];
    gather(0, gcur);

    for (int ti = 0; ti < NT; ti++) {
        // stage A (fp32 -> f16 hi/lo)
        {
            const int kk0 = 4 * aq, kk1 = kk0 + 16;
#pragma unroll
            for (int i = 0; i < 4; i++) {
                float v = gcur[i];
                _Float16 h = (_Float16)v;
                Ah[am][kk0 + i] = h;
                Al[am][kk0 + i] = (_Float16)(v - (float)h);
                v = gcur[4 + i];
                h = (_Float16)v;
                Ah[am][kk1 + i] = h;
                Al[am][kk1 + i] = (_Float16)(v - (float)h);
            }
        }
        // stage B (pre-split weights)
        const int k0 = ti * KT;
#pragma unroll
        for (int j = 0; j < KT / KSTEP; j++) {
            const int kk = bk + KSTEP * j;
            const int gk = k0 + kk;
            const _Float16* ph;
            const _Float16* pl;
            if (gk < CIN) {
                ph = WlhB + (size_t)gk * COUT + n0 + bn;
                pl = WllB + (size_t)gk * COUT + n0 + bn;
            } else {
                ph = WrhB + (size_t)(gk - CIN) * COUT + n0 + bn;
                pl = WrlB + (size_t)(gk - CIN) * COUT + n0 + bn;
            }
            const half4 vh = *(const half4*)ph;
            const half4 vl = *(const half4*)pl;
#pragma unroll
            for (int i = 0; i < 4; i++) {
                Bh[bn + i][kk]  = vh[i];
                Blo[bn + i][kk] = vl[i];
            }
        }
        __syncthreads();

        // prefetch next tile's fragment (overlaps MFMA below)
        float gnext[8];
        if (ti + 1 < NT) {
            gather(ti + 1, gnext);
        } else {
#pragma unroll
            for (int i = 0; i < 8; i++) gnext[i] = 0.f;
        }

        // MFMA 3-pass over tile ti
        {
            half8 ah[4], alo[4];
#pragma unroll
            for (int mt = 0; mt < 4; mt++) {
                ah[mt]  = *(const half8*)&Ah[mt * 16 + lx][qd * 8];
                alo[mt] = *(const half8*)&Al[mt * 16 + lx][qd * 8];
            }
#pragma unroll
            for (int nt = 0; nt < NTN; nt++) {
                const int bcol = wv * (16 * NTN) + nt * 16 + lx;
                const half8 bhv = *(const half8*)&Bh[bcol][qd * 8];
                const half8 blv = *(const half8*)&Blo[bcol][qd * 8];
#pragma unroll
                for (int mt = 0; mt < 4; mt++) {
                    acc[mt][nt] = __builtin_amdgcn_mfma_f32_16x16x32_f16(ah[mt],  bhv, acc[mt][nt], 0, 0, 0);
                    acc[mt][nt] = __builtin_amdgcn_mfma_f32_16x16x32_f16(alo[mt], bhv, acc[mt][nt], 0, 0, 0);
                    acc[mt][nt] = __builtin_amdgcn_mfma_f32_16x16x32_f16(ah[mt],  blv, acc[mt][nt], 0, 0, 0);
                }
            }
        }
        __syncthreads();

#pragma unroll
        for (int i = 0; i < 8; i++) gcur[i] = gnext[i];
    }

    // epilogue: lane cols are n0 + wv*(16*NTN) + nt*16 + lx
    float blv[NTN], w0[NTN], w1[NTN];
    int cols[NTN];
#pragma unroll
    for (int nt = 0; nt < NTN; nt++) {
        cols[nt] = n0 + wv * (16 * NTN) + nt * 16 + lx;
        blv[nt] = bias[d * COUT + cols[nt]];
        w0[nt]  = Wf[(size_t)(wf_off + cols[nt]) * 2 + 0];
        w1[nt]  = Wf[(size_t)(wf_off + cols[nt]) * 2 + 1];
    }
#pragma unroll
    for (int mt = 0; mt < 4; mt++)
#pragma unroll
    for (int r = 0; r < 4; r++) {
        const int node = rowid[mt * 16 + qd * 4 + r];
        float p0 = 0.f, p1 = 0.f;
        if (node >= 0) {
            float h[NTN];
#pragma unroll
            for (int nt = 0; nt < NTN; nt++) {
                h[nt] = acc[mt][nt][r] + blv[nt];
                p0 = fmaf(h[nt], w0[nt], p0);
                p1 = fmaf(h[nt], w1[nt], p1);
            }
            if constexpr (POOL_FUSE) {
                float* pr = pool + (size_t)batch[node] * 256;
#pragma unroll
                for (int nt = 0; nt < NTN; nt++) atomicAdd(&pr[cols[nt]], h[nt]);
            } else {
                float* orow = out0 + (size_t)node * COUT;
#pragma unroll
                for (int nt = 0; nt < NTN; nt++) orow[cols[nt]] = h[nt];
            }
        }
#pragma unroll
        for (int s = 1; s < 16; s <<= 1) {
            p0 += __shfl_xor(p0, s, 64);
            p1 += __shfl_xor(p1, s, 64);
        }
        if (node >= 0 && lx == 0) {
            atomicAdd(&logits[(size_t)node * 2 + 0], p0);
            atomicAdd(&logits[(size_t)node * 2 + 1], p1);
        }
    }
}

// ---------------- layer-2b: full-width MFMA GEMM, in-place ----------------

// h2 = [m2 | h1] @ [Wl2; Wr2] + bl2; K2 = 256, COUT = 256, one block owns its
// 64 rows end-to-end (race-free in-place: reads drain before final barrier).
__launch_bounds__(256, 3)
__global__ void k_gemm2b(float* __restrict__ buf0, float* __restrict__ buf1,
                         const _Float16* __restrict__ wlh, const _Float16* __restrict__ wll,
                         const _Float16* __restrict__ wrh, const _Float16* __restrict__ wrl,
                         const float* __restrict__ bias, const float* __restrict__ Wf,
                         const int* __restrict__ perm, const int* __restrict__ deg,
                         float* __restrict__ logits) {
    constexpr int COUT = 256;
    __shared__ _Float16 Ah[BM][KP];
    __shared__ _Float16 Al[BM][KP];
    __shared__ _Float16 Bh[256][KP];
    __shared__ _Float16 Blo[256][KP];
    __shared__ int rowid[BM];

    const int t  = threadIdx.x;
    const int m0 = blockIdx.x * BM;

    if (t < BM) rowid[t] = perm[m0 + t];
    __syncthreads();
    if (rowid[0] < 0) return;

    const int d = min(deg[rowid[0]], MAXD);
    const _Float16* WlhB = wlh + (size_t)d * 128 * COUT;
    const _Float16* WllB = wll + (size_t)d * 128 * COUT;
    const _Float16* WrhB = wrh + (size_t)d * 128 * COUT;
    const _Float16* WrlB = wrl + (size_t)d * 128 * COUT;

    const int am = t & 63, aq = t >> 6;
    const int anode = rowid[am];
    const int bn = (t & 63) * 4, bk = t >> 6;
    const int lx = t & 15, qd = (t >> 4) & 3, wv = t >> 6;

    f32x4 acc[4][4];
#pragma unroll
    for (int mt = 0; mt < 4; mt++)
#pragma unroll
        for (int nt = 0; nt < 4; nt++) acc[mt][nt] = (f32x4)0.f;

    for (int k0 = 0; k0 < 256; k0 += KT) {
        // stage A (own row, fp32 -> hi/lo)
        {
            const int gk0 = k0 + 4 * aq;
            float4 v0 = make_float4(0.f, 0.f, 0.f, 0.f);
            float4 v1 = v0;
            if (anode >= 0) {
                const float* r = (gk0 < 128) ? buf0 + (size_t)anode * 128 + gk0
                                             : buf1 + (size_t)anode * 128 + (gk0 - 128);
                v0 = *(const float4*)r;
                v1 = *(const float4*)(r + 16);
            }
            const int kk0 = 4 * aq, kk1 = kk0 + 16;
            const float g[8] = {v0.x, v0.y, v0.z, v0.w, v1.x, v1.y, v1.z, v1.w};
#pragma unroll
            for (int i = 0; i < 4; i++) {
                _Float16 h = (_Float16)g[i];
                Ah[am][kk0 + i] = h;
                Al[am][kk0 + i] = (_Float16)(g[i] - (float)h);
                h = (_Float16)g[4 + i];
                Ah[am][kk1 + i] = h;
                Al[am][kk1 + i] = (_Float16)(g[4 + i] - (float)h);
            }
        }
        // stage B
#pragma unroll
        for (int j = 0; j < 8; j++) {
            const int kk = bk + 4 * j;
            const int gk = k0 + kk;
            const _Float16* ph;
            const _Float16* pl;
            if (gk < 128) {
                ph = WlhB + (size_t)gk * COUT + bn;
                pl = WllB + (size_t)gk * COUT + bn;
            } else {
                ph = WrhB + (size_t)(gk - 128) * COUT + bn;
                pl = WrlB + (size_t)(gk - 128) * COUT + bn;
            }
            const half4 vh = *(const half4*)ph;
            const half4 vl = *(const half4*)pl;
#pragma unroll
            for (int i = 0; i < 4; i++) {
                Bh[bn + i][kk]  = vh[i];
                Blo[bn + i][kk] = vl[i];
            }
        }
        __syncthreads();
        {
            half8 ah[4], alo[4];
#pragma unroll
            for (int mt = 0; mt < 4; mt++) {
                ah[mt]  = *(const half8*)&Ah[mt * 16 + lx][qd * 8];
                alo[mt] = *(const half8*)&Al[mt * 16 + lx][qd * 8];
            }
#pragma unroll
            for (int nt = 0; nt < 4; nt++) {
                const int bcol = wv * 64 + nt * 16 + lx;
                const half8 bhv = *(const half8*)&Bh[bcol][qd * 8];
                const half8 blv = *(const half8*)&Blo[bcol][qd * 8];
#pragma unroll
                for (int mt = 0; mt < 4; mt++) {
                    acc[mt][nt] = __builtin_amdgcn_mfma_f32_16x16x32_f16(ah[mt],  bhv, acc[mt][nt], 0, 0, 0);
                    acc[mt][nt] = __builtin_amdgcn_mfma_f32_16x16x32_f16(alo[mt], bhv, acc[mt][nt], 0, 0, 0);
                    acc[mt][nt] = __builtin_amdgcn_mfma_f32_16x16x32_f16(ah[mt],  blv, acc[mt][nt], 0, 0, 0);
                }
            }
        }
        __syncthreads();
    }

    // epilogue: lane cols wv*64 + nt*16 + lx; in-place split write
    float blv[4], w0[4], w1[4];
    int cols[4];
#pragma unroll
    for (int nt = 0; nt < 4; nt++) {
        cols[nt] = wv * 64 + nt * 16 + lx;
        blv[nt] = bias[d * COUT + cols[nt]];
        w0[nt]  = Wf[(size_t)(256 + cols[nt]) * 2 + 0];
        w1[nt]  = Wf[(size_t)(256 + cols[nt]) * 2 + 1];
    }
#pragma unroll
    for (int mt = 0; mt < 4; mt++)
#pragma unroll
    for (int r = 0; r < 4; r++) {
        const int node = rowid[mt * 16 + qd * 4 + r];
        float p0 = 0.f, p1 = 0.f;
        if (node >= 0) {
#pragma unroll
            for (int nt = 0; nt < 4; nt++) {
                const float h = acc[mt][nt][r] + blv[nt];
                p0 = fmaf(h, w0[nt], p0);
                p1 = fmaf(h, w1[nt], p1);
                if (cols[nt] < 128) buf0[(size_t)node * 128 + cols[nt]] = h;
                else                buf1[(size_t)node * 128 + cols[nt] - 128] = h;
            }
        }
#pragma unroll
        for (int s = 1; s < 16; s <<= 1) {
            p0 += __shfl_xor(p0, s, 64);
            p1 += __shfl_xor(p1, s, 64);
        }
        if (node >= 0 && lx == 0) {
            atomicAdd(&logits[(size_t)node * 2 + 0], p0);
            atomicAdd(&logits[(size_t)node * 2 + 1], p1);
        }
    }
}

// ---------------- pooling / output ----------------

__global__ void k_pool_logits(const float* __restrict__ pool, const float* __restrict__ Wf,
                              const float* __restrict__ bf, float* __restrict__ pl) {
    int g = blockIdx.x * 4 + (threadIdx.x >> 6);
    int lane = threadIdx.x & 63;
    const float* pr = pool + (size_t)g * 256;
    float p0 = 0.f, p1 = 0.f;
#pragma unroll
    for (int j = 0; j < 4; j++) {
        int k = lane + 64 * j;
        float v = pr[k];
        p0 = fmaf(v, Wf[(size_t)(768 + k) * 2 + 0], p0);
        p1 = fmaf(v, Wf[(size_t)(768 + k) * 2 + 1], p1);
    }
#pragma unroll
    for (int s = 1; s < 64; s <<= 1) {
        p0 += __shfl_xor(p0, s, 64);
        p1 += __shfl_xor(p1, s, 64);
    }
    if (lane == 0) {
        pl[(size_t)g * 2 + 0] = p0 + bf[0];
        pl[(size_t)g * 2 + 1] = p1 + bf[1];
    }
}

__global__ void k_final(const float* __restrict__ logits, const float* __restrict__ pl,
                        const int* __restrict__ batch, float* __restrict__ outp) {
    int i = blockIdx.x * 256 + threadIdx.x;
    if (i < NN) {
        int g = batch[i];
        float l0 = logits[(size_t)i * 2 + 0] + pl[(size_t)g * 2 + 0];
        float l1 = logits[(size_t)i * 2 + 1] + pl[(size_t)g * 2 + 1];
        float m = fmaxf(l0, l1);
        float e0 = expf(l0 - m), e1 = expf(l1 - m);
        float inv = 1.f / (e0 + e1);
        outp[(size_t)i * 2 + 0] = e0 * inv;
        outp[(size_t)i * 2 + 1] = e1 * inv;
    }
}

}  // namespace

extern "C" void kernel_launch(void* const* d_in, const int* in_sizes, int n_in,
                              void* d_out, int out_size, void* d_ws, size_t ws_size,
                              hipStream_t stream) {
    const float* x     = (const float*)d_in[0];
    const int*   ei    = (const int*)d_in[1];
    const int*   batch = (const int*)d_in[2];
    const float* Wl0 = (const float*)d_in[3];  const float* bl0 = (const float*)d_in[4];
    const float* Wr0 = (const float*)d_in[5];
    const float* Wl1 = (const float*)d_in[6];  const float* bl1 = (const float*)d_in[7];
    const float* Wr1 = (const float*)d_in[8];
    const float* Wl2 = (const float*)d_in[9];  const float* bl2 = (const float*)d_in[10];
    const float* Wr2 = (const float*)d_in[11];
    const float* Wl3 = (const float*)d_in[12]; const float* bl3 = (const float*)d_in[13];
    const float* Wr3 = (const float*)d_in[14];
    const float* Wf  = (const float*)d_in[15]; const float* bf  = (const float*)d_in[16];
    const int* src = ei;
    const int* dst = ei + NE;
    float* outp = (float*)d_out;
    (void)in_sizes; (void)n_in;

    // workspace bump allocator (256B aligned).  Total ≈ 224 MB (ws is 256 MB).
    char* w = (char*)d_ws;
    auto alloc = [&](size_t bytes) -> void* {
        void* p = (void*)w;
        w += (bytes + 255) & ~(size_t)255;
        return p;
    };
    // zero-init region (contiguous): deg .. pool
    int*   deg    = (int*)alloc((size_t)NN * 4);
    int*   bcnt   = (int*)alloc(32);
    int*   bcur   = (int*)alloc(32);
    float* logits = (float*)alloc((size_t)NN * 2 * 4);
    float* pool   = (float*)alloc((size_t)NG * 256 * 4);
    size_t zero_words = (size_t)(w - (char*)deg) / 4;
    // fully-written-by-kernel regions
    int*   bpad    = (int*)alloc(32);
    int*   perm    = (int*)alloc((size_t)PERMN * 4);      // filled with -1
    int*   row_ptr = (int*)alloc((size_t)(NN + 1) * 4);
    int*   cursor  = (int*)alloc((size_t)NN * 4);
    int*   col     = (int*)alloc((size_t)NE * 4);
    int*   part    = (int*)alloc(1024 * 4);
    float* pl      = (float*)alloc((size_t)NG * 2 * 4);
    _Float16* whi  = (_Float16*)alloc(WTOT * 2);          // pre-split weights hi
    _Float16* wlo  = (_Float16*)alloc(WTOT * 2);          // pre-split weights lo
    float* bufA    = (float*)alloc((size_t)NN * 128 * 4); // h0 -> m2 -> h2[:,0:128)
    float* bufB    = (float*)alloc((size_t)NN * 128 * 4); // h1 -> h2[:,128:256)

    size_t required = (size_t)(w - (char*)d_ws);
    if (required > ws_size) {
        k_report<<<(out_size + 255) / 256, 256, 0, stream>>>(
            outp, (float)(double)(ws_size >> 20), out_size);
        return;
    }

    dim3 b256(256);
    k_memset32<<<(int)((zero_words + 255) / 256), b256, 0, stream>>>((int*)deg, 0, (int)zero_words);
    k_memset32<<<(PERMN + 255) / 256, b256, 0, stream>>>(perm, -1, PERMN);

    // pre-split all weights to f16 hi/lo
    k_wsplit<<<(int)(S_L0 + 255) / 256, b256, 0, stream>>>(Wl0, whi + O_WL0, wlo + O_WL0, (int)S_L0);
    k_wsplit<<<(int)(S_L0 + 255) / 256, b256, 0, stream>>>(Wr0, whi + O_WR0, wlo + O_WR0, (int)S_L0);
    k_wsplit<<<(int)(S_L1 + 255) / 256, b256, 0, stream>>>(Wl1, whi + O_WL1, wlo + O_WL1, (int)S_L1);
    k_wsplit<<<(int)(S_L1 + 255) / 256, b256, 0, stream>>>(Wr1, whi + O_WR1, wlo + O_WR1, (int)S_L1);
    k_wsplit<<<(int)(S_L2 + 255) / 256, b256, 0, stream>>>(Wl2, whi + O_WL2, wlo + O_WL2, (int)S_L2);
    k_wsplit<<<(int)(S_L2 + 255) / 256, b256, 0, stream>>>(Wr2, whi + O_WR2, wlo + O_WR2, (int)S_L2);
    k_wsplit<<<(int)(S_L3 + 255) / 256, b256, 0, stream>>>(Wl3, whi + O_WL3, wlo + O_WL3, (int)S_L3);
    k_wsplit<<<(int)(S_L3 + 255) / 256, b256, 0, stream>>>(Wr3, whi + O_WR3, wlo + O_WR3, (int)S_L3);

    k_count_deg<<<NE / 256, b256, 0, stream>>>(dst, deg);
    k_scan_part<<<782, b256, 0, stream>>>(deg, part);
    k_scan_single<<<1, 1024, 0, stream>>>(part, 782);
    k_scan_final<<<782, b256, 0, stream>>>(deg, part, row_ptr, cursor);
    k_fill_csr<<<NE / 256, b256, 0, stream>>>(src, dst, cursor, col);
    k_bucket_count<<<782, b256, 0, stream>>>(deg, bcnt);
    k_bucket_scan<<<1, 64, 0, stream>>>(bcnt, bpad);
    k_scatter<<<782, b256, 0, stream>>>(deg, bpad, bcur, perm);

    // Layer 0: in=x(64) -> h0=bufA(128)
    k_transform<64, 0, 128, 128, false><<<dim3(NBLK, 1), b256, 0, stream>>>(
        x, nullptr, row_ptr, col, whi + O_WL0, wlo + O_WL0, whi + O_WR0, wlo + O_WR0,
        bl0, Wf, perm, deg, nullptr, bufA, nullptr, logits, 0);
    // Layer 1: in=bufA(128) -> h1=bufB(128)
    k_transform<128, 0, 128, 128, false><<<dim3(NBLK, 1), b256, 0, stream>>>(
        bufA, nullptr, row_ptr, col, whi + O_WL1, wlo + O_WL1, whi + O_WR1, wlo + O_WR1,
        bl1, Wf, perm, deg, nullptr, bufB, nullptr, logits, 128);
    // Layer 2a: m2 = gather-sum(h1) -> bufA
    k_aggregate128<<<NN / 4, b256, 0, stream>>>(bufB, row_ptr, col, bufA);
    // Layer 2b: h2 = [m2|h1] @ [Wl2;Wr2] + bl2, in place -> [bufA|bufB]
    k_gemm2b<<<dim3(NBLK), b256, 0, stream>>>(
        bufA, bufB, whi + O_WL2, wlo + O_WL2, whi + O_WR2, wlo + O_WR2,
        bl2, Wf, perm, deg, logits);
    // Layer 3: in=[bufA|bufB](256) -> logits chunk + pool (h3 never stored;
    // BN=256 single y-block halves the gather traffic vs two y-blocks)
    k_transform<128, 128, 256, 256, true><<<dim3(NBLK, 1), b256, 0, stream>>>(
        bufA, bufB, row_ptr, col, whi + O_WL3, wlo + O_WL3, whi + O_WR3, wlo + O_WR3,
        bl3, Wf, perm, deg, batch, nullptr, pool, logits, 512);

    k_pool_logits<<<NG / 4, b256, 0, stream>>>(pool, Wf, bf, pl);
    k_final<<<782, b256, 0, stream>>>(logits, pl, batch, outp);
}

// Round 10
// 2332.647 us; speedup vs baseline: 2.2704x; 1.8504x over previous
//
#include <hip/hip_runtime.h>
#include <cstdint>
#include <cstddef>

namespace {

constexpr int NN   = 200000;   // nodes
constexpr int NE   = 800000;   // edges
constexpr int NG   = 4096;     // graphs
constexpr int MAXD = 5;

constexpr int BM = 64;
constexpr int KT = 32;
constexpr int KP = KT + 8;     // padded LDS row (f16), 80 B rows keep 16B align
constexpr int NBC = (NN + 255) / 256;           // 782 preprocessing blocks
constexpr int NBLK  = (NN + BM - 1) / BM + 6;   // 3131 (bucket padding)
constexpr int PERMN = NBLK * BM;                // 200384

typedef _Float16 half8 __attribute__((ext_vector_type(8)));
typedef _Float16 half4 __attribute__((ext_vector_type(4)));
typedef float    f32x4 __attribute__((ext_vector_type(4)));

// weight-split buffer element offsets
constexpr size_t S_L0 = (size_t)6 * 64 * 128;    // 49152
constexpr size_t S_L1 = (size_t)6 * 128 * 128;   // 98304
constexpr size_t S_L2 = (size_t)6 * 128 * 256;   // 196608
constexpr size_t S_L3 = (size_t)6 * 256 * 256;   // 393216
constexpr size_t O_WL0 = 0;
constexpr size_t O_WR0 = O_WL0 + S_L0;
constexpr size_t O_WL1 = O_WR0 + S_L0;
constexpr size_t O_WR1 = O_WL1 + S_L1;
constexpr size_t O_WL2 = O_WR1 + S_L1;
constexpr size_t O_WR2 = O_WL2 + S_L2;
constexpr size_t O_WL3 = O_WR2 + S_L2;
constexpr size_t O_WR3 = O_WL3 + S_L3;
constexpr size_t WTOT  = O_WR3 + S_L3;           // 1,474,560 elements

// ---------------- init / diagnostic ----------------

__global__ void k_memset32(int* __restrict__ p, int v, int n) {
    int i = blockIdx.x * 256 + threadIdx.x;
    if (i < n) p[i] = v;
}

__global__ void k_report(float* __restrict__ outp, float v, int n) {
    int i = blockIdx.x * 256 + threadIdx.x;
    if (i < n) outp[i] = v;
}

// fp32 -> f16 hi/lo split (exact: v = hi + lo + O(2^-22 v))
__global__ void k_wsplit(const float* __restrict__ w, _Float16* __restrict__ hi,
                         _Float16* __restrict__ lo, int n) {
    int i = blockIdx.x * 256 + threadIdx.x;
    if (i < n) {
        float v = w[i];
        _Float16 h = (_Float16)v;
        hi[i] = h;
        lo[i] = (_Float16)(v - (float)h);
    }
}

// ---------------- graph preprocessing ----------------

__global__ void k_count_deg(const int* __restrict__ dst, int* __restrict__ deg) {
    int e = blockIdx.x * 256 + threadIdx.x;
    if (e < NE) atomicAdd(&deg[dst[e]], 1);
}

__global__ void k_scan_part(const int* __restrict__ deg, int* __restrict__ part) {
    __shared__ int s[256];
    int t = threadIdx.x, i = blockIdx.x * 256 + t;
    s[t] = (i < NN) ? deg[i] : 0;
    __syncthreads();
    for (int st = 128; st > 0; st >>= 1) {
        if (t < st) s[t] += s[t + st];
        __syncthreads();
    }
    if (t == 0) part[blockIdx.x] = s[0];
}

__global__ void k_scan_single(int* __restrict__ part, int nb) {
    __shared__ int s[1024];
    int t = threadIdx.x;
    int v0 = (t < nb) ? part[t] : 0;
    s[t] = v0;
    __syncthreads();
    for (int off = 1; off < 1024; off <<= 1) {
        int v = (t >= off) ? s[t - off] : 0;
        __syncthreads();
        s[t] += v;
        __syncthreads();
    }
    if (t < nb) part[t] = s[t] - v0;
}

__global__ void k_scan_final(const int* __restrict__ deg, const int* __restrict__ part,
                             int* __restrict__ row_ptr, int* __restrict__ cursor) {
    __shared__ int s[256];
    int t = threadIdx.x, i = blockIdx.x * 256 + t;
    int v0 = (i < NN) ? deg[i] : 0;
    s[t] = v0;
    __syncthreads();
    for (int off = 1; off < 256; off <<= 1) {
        int v = (t >= off) ? s[t - off] : 0;
        __syncthreads();
        s[t] += v;
        __syncthreads();
    }
    if (i < NN) {
        int excl = s[t] - v0 + part[blockIdx.x];
        row_ptr[i] = excl;
        cursor[i]  = excl;
        if (i == NN - 1) row_ptr[NN] = excl + v0;
    }
}

__global__ void k_fill_csr(const int* __restrict__ src, const int* __restrict__ dst,
                           int* __restrict__ cursor, int* __restrict__ col) {
    int e = blockIdx.x * 256 + threadIdx.x;
    if (e < NE) {
        int d = dst[e];
        int slot = atomicAdd(&cursor[d], 1);
        col[slot] = src[e];
    }
}

// -- two-level bucket counting sort (replaces 200k global atomics on 6 addrs,
//    which serialized at ~1 ms: round-9 k_scatter showed VALUBusy 0.006%) --

// per-block LDS histogram of degree buckets
__global__ void k_bucket_blockcount(const int* __restrict__ deg, int* __restrict__ blkcnt) {
    __shared__ int h[6];
    int t = threadIdx.x;
    if (t < 6) h[t] = 0;
    __syncthreads();
    int i = blockIdx.x * 256 + t;
    if (i < NN) atomicAdd(&h[min(deg[i], MAXD)], 1);
    __syncthreads();
    if (t < 6) blkcnt[t * NBC + blockIdx.x] = h[t];   // bucket-major
}

// single block: in-place exclusive scan per bucket over blocks + padded bases
__global__ void k_bucket_scanall(int* __restrict__ blkcnt, int* __restrict__ bpad) {
    __shared__ int tot[6];
    int t = threadIdx.x;
    if (t < 6) {
        int run = 0;
        for (int j = 0; j < NBC; j++) {
            int v = blkcnt[t * NBC + j];
            blkcnt[t * NBC + j] = run;
            run += v;
        }
        tot[t] = run;
    }
    __syncthreads();
    if (t == 0) {
        int off = 0;
        for (int b = 0; b < 6; b++) {
            bpad[b] = off;
            off += ((tot[b] + BM - 1) / BM) * BM;
        }
        bpad[6] = off;
    }
}

// scatter using block-local LDS ranks (no contended global atomics)
__global__ void k_scatter2(const int* __restrict__ deg, const int* __restrict__ blkcnt,
                           const int* __restrict__ bpad, int* __restrict__ perm) {
    __shared__ int base[6];
    int t = threadIdx.x;
    if (t < 6) base[t] = bpad[t] + blkcnt[t * NBC + blockIdx.x];
    __syncthreads();
    int i = blockIdx.x * 256 + t;
    if (i < NN) {
        int b = min(deg[i], MAXD);
        int pos = atomicAdd(&base[b], 1);   // LDS atomic, block-local
        perm[pos] = i;
    }
}

// ---------------- layer-2a: plain neighbor-sum aggregate ----------------

__global__ void k_aggregate128(const float* __restrict__ hin, const int* __restrict__ row_ptr,
                               const int* __restrict__ col, float* __restrict__ msg) {
    int node = blockIdx.x * 4 + (threadIdx.x >> 6);
    int lane = threadIdx.x & 63;
    int s = row_ptr[node], e = row_ptr[node + 1];
    float2 acc = make_float2(0.f, 0.f);
    for (int p = s; p < e; p++) {
        const float2 v = *(const float2*)(hin + (size_t)col[p] * 128 + lane * 2);
        acc.x += v.x; acc.y += v.y;
    }
    *(float2*)(msg + (size_t)node * 128 + lane * 2) = acc;
}

// ---------------- fused aggregate + transform (MFMA f16-split) ----------------

// out[i] = [sum_{j->i} hin[j], hin[i]] @ [Wl[d]; Wr[d]] + bl[d], d = bucket(i).
// Core is mfma_f32_16x16x32_f16, 3-pass f16 hi/lo split (exact to ~2^-22 rel).
// Gather prefetch pipeline retained; weights pre-split to f16 hi/lo.
// A/B LDS layout [row][k] f16, row stride KP=40 (16B-aligned, padded).
// POOL_FUSE: no h store; rows atomically accumulated into pool[batch[node]].
// Epilogue banks this chunk's Wf contribution into per-node logits.
template <int C0, int C1, int COUT, int BN_, bool POOL_FUSE>
__launch_bounds__(256, (BN_ == 256) ? 3 : 4)
__global__ void k_transform(const float* __restrict__ hin0, const float* __restrict__ hin1,
                            const int* __restrict__ row_ptr, const int* __restrict__ col,
                            const _Float16* __restrict__ wlh, const _Float16* __restrict__ wll,
                            const _Float16* __restrict__ wrh, const _Float16* __restrict__ wrl,
                            const float* __restrict__ bias, const float* __restrict__ Wf,
                            const int* __restrict__ perm, const int* __restrict__ deg,
                            const int* __restrict__ batch,
                            float* __restrict__ out0, float* __restrict__ pool,
                            float* __restrict__ logits, int wf_off) {
    constexpr int CIN = C0 + C1;
    constexpr int NW0 = C0 / 32;
    constexpr int NW  = CIN / 32;
    constexpr int NT  = 2 * NW;
    constexpr int NTN = BN_ / 64;        // N-tiles per wave (2 or 4)
    constexpr int LPR = BN_ / 4;         // B-staging lanes per k-row
    constexpr int KSTEP = 256 / LPR;     // k-rows per staging pass
    __shared__ _Float16 Ah[BM][KP];
    __shared__ _Float16 Al[BM][KP];
    __shared__ _Float16 Bh[BN_][KP];
    __shared__ _Float16 Blo[BN_][KP];
    __shared__ int rowid[BM];

    const int t  = threadIdx.x;
    const int m0 = blockIdx.x * BM;
    const int n0 = blockIdx.y * BN_;

    if (t < BM) rowid[t] = perm[m0 + t];
    __syncthreads();
    if (rowid[0] < 0) return;  // fully-padded block (uniform exit)

    const int d = min(deg[rowid[0]], MAXD);
    const _Float16* WlhB = wlh + (size_t)d * CIN * COUT;
    const _Float16* WllB = wll + (size_t)d * CIN * COUT;
    const _Float16* WrhB = wrh + (size_t)d * CIN * COUT;
    const _Float16* WrlB = wrl + (size_t)d * CIN * COUT;

    const int am = t & 63, aq = t >> 6;
    const int anode = rowid[am];
    int es = 0, ee = 0;
    if (anode >= 0) { es = row_ptr[anode]; ee = row_ptr[anode + 1]; }
    const int bn = (t % LPR) * 4, bk = t / LPR;
    const int lx = t & 15, qd = (t >> 4) & 3, wv = t >> 6;

    // gather A-fragment for tile ti into g[8] (constant-indexed scalars)
    auto gather = [&](int ti, float* g) {
#pragma unroll
        for (int i = 0; i < 8; i++) g[i] = 0.f;
        if (ti < NW) {
            const bool lo = (C1 == 0) || (ti < NW0);
            const float* base = lo ? hin0 : hin1;
            const int stride  = lo ? C0 : C1;
            const int off     = (lo ? 32 * ti : 32 * (ti - NW0)) + 4 * aq;
            for (int p = es; p < ee; p++) {
                const float* r = base + (size_t)col[p] * stride + off;
                const float4 a = *(const float4*)r;
                const float4 b = *(const float4*)(r + 16);
                g[0] += a.x; g[1] += a.y; g[2] += a.z; g[3] += a.w;
                g[4] += b.x; g[5] += b.y; g[6] += b.z; g[7] += b.w;
            }
        } else if (anode >= 0) {
            const int e = (ti - NW) * 32 + 4 * aq;
            const float* r = (C1 == 0 || e < C0)
                                 ? hin0 + (size_t)anode * C0 + e
                                 : hin1 + (size_t)anode * C1 + (e - C0);
            const float4 a = *(const float4*)r;
            const float4 b = *(const float4*)(r + 16);
            g[0] = a.x; g[1] = a.y; g[2] = a.z; g[3] = a.w;
            g[4] = b.x; g[5] = b.y; g[6] = b.z; g[7] = b.w;
        }
    };

    f32x4 acc[4][NTN];
#pragma unroll
    for (int mt = 0; mt < 4; mt++)
#pragma unroll
        for (int nt = 0; nt < NTN; nt++) acc[mt][nt] = (f32x4)0.f;

    float gcur[8];
    gather(0, gcur);

    for (int ti = 0; ti < NT; ti++) {
        // stage A (fp32 -> f16 hi/lo)
        {
            const int kk0 = 4 * aq, kk1 = kk0 + 16;
#pragma unroll
            for (int i = 0; i < 4; i++) {
                float v = gcur[i];
                _Float16 h = (_Float16)v;
                Ah[am][kk0 + i] = h;
                Al[am][kk0 + i] = (_Float16)(v - (float)h);
                v = gcur[4 + i];
                h = (_Float16)v;
                Ah[am][kk1 + i] = h;
                Al[am][kk1 + i] = (_Float16)(v - (float)h);
            }
        }
        // stage B (pre-split weights)
        const int k0 = ti * KT;
#pragma unroll
        for (int j = 0; j < KT / KSTEP; j++) {
            const int kk = bk + KSTEP * j;
            const int gk = k0 + kk;
            const _Float16* ph;
            const _Float16* pl;
            if (gk < CIN) {
                ph = WlhB + (size_t)gk * COUT + n0 + bn;
                pl = WllB + (size_t)gk * COUT + n0 + bn;
            } else {
                ph = WrhB + (size_t)(gk - CIN) * COUT + n0 + bn;
                pl = WrlB + (size_t)(gk - CIN) * COUT + n0 + bn;
            }
            const half4 vh = *(const half4*)ph;
            const half4 vl = *(const half4*)pl;
#pragma unroll
            for (int i = 0; i < 4; i++) {
                Bh[bn + i][kk]  = vh[i];
                Blo[bn + i][kk] = vl[i];
            }
        }
        __syncthreads();

        // prefetch next tile's fragment (overlaps MFMA below)
        float gnext[8];
        if (ti + 1 < NT) {
            gather(ti + 1, gnext);
        } else {
#pragma unroll
            for (int i = 0; i < 8; i++) gnext[i] = 0.f;
        }

        // MFMA 3-pass over tile ti
        {
            half8 ah[4], alo[4];
#pragma unroll
            for (int mt = 0; mt < 4; mt++) {
                ah[mt]  = *(const half8*)&Ah[mt * 16 + lx][qd * 8];
                alo[mt] = *(const half8*)&Al[mt * 16 + lx][qd * 8];
            }
#pragma unroll
            for (int nt = 0; nt < NTN; nt++) {
                const int bcol = wv * (16 * NTN) + nt * 16 + lx;
                const half8 bhv = *(const half8*)&Bh[bcol][qd * 8];
                const half8 blv = *(const half8*)&Blo[bcol][qd * 8];
#pragma unroll
                for (int mt = 0; mt < 4; mt++) {
                    acc[mt][nt] = __builtin_amdgcn_mfma_f32_16x16x32_f16(ah[mt],  bhv, acc[mt][nt], 0, 0, 0);
                    acc[mt][nt] = __builtin_amdgcn_mfma_f32_16x16x32_f16(alo[mt], bhv, acc[mt][nt], 0, 0, 0);
                    acc[mt][nt] = __builtin_amdgcn_mfma_f32_16x16x32_f16(ah[mt],  blv, acc[mt][nt], 0, 0, 0);
                }
            }
        }
        __syncthreads();

#pragma unroll
        for (int i = 0; i < 8; i++) gcur[i] = gnext[i];
    }

    // epilogue: lane cols are n0 + wv*(16*NTN) + nt*16 + lx
    float blv[NTN], w0[NTN], w1[NTN];
    int cols[NTN];
#pragma unroll
    for (int nt = 0; nt < NTN; nt++) {
        cols[nt] = n0 + wv * (16 * NTN) + nt * 16 + lx;
        blv[nt] = bias[d * COUT + cols[nt]];
        w0[nt]  = Wf[(size_t)(wf_off + cols[nt]) * 2 + 0];
        w1[nt]  = Wf[(size_t)(wf_off + cols[nt]) * 2 + 1];
    }
#pragma unroll
    for (int mt = 0; mt < 4; mt++)
#pragma unroll
    for (int r = 0; r < 4; r++) {
        const int node = rowid[mt * 16 + qd * 4 + r];
        float p0 = 0.f, p1 = 0.f;
        if (node >= 0) {
            float h[NTN];
#pragma unroll
            for (int nt = 0; nt < NTN; nt++) {
                h[nt] = acc[mt][nt][r] + blv[nt];
                p0 = fmaf(h[nt], w0[nt], p0);
                p1 = fmaf(h[nt], w1[nt], p1);
            }
            if constexpr (POOL_FUSE) {
                float* pr = pool + (size_t)batch[node] * 256;
#pragma unroll
                for (int nt = 0; nt < NTN; nt++) atomicAdd(&pr[cols[nt]], h[nt]);
            } else {
                float* orow = out0 + (size_t)node * COUT;
#pragma unroll
                for (int nt = 0; nt < NTN; nt++) orow[cols[nt]] = h[nt];
            }
        }
#pragma unroll
        for (int s = 1; s < 16; s <<= 1) {
            p0 += __shfl_xor(p0, s, 64);
            p1 += __shfl_xor(p1, s, 64);
        }
        if (node >= 0 && lx == 0) {
            atomicAdd(&logits[(size_t)node * 2 + 0], p0);
            atomicAdd(&logits[(size_t)node * 2 + 1], p1);
        }
    }
}

// ---------------- layer-2b: full-width MFMA GEMM, in-place ----------------

__launch_bounds__(256, 3)
__global__ void k_gemm2b(float* __restrict__ buf0, float* __restrict__ buf1,
                         const _Float16* __restrict__ wlh, const _Float16* __restrict__ wll,
                         const _Float16* __restrict__ wrh, const _Float16* __restrict__ wrl,
                         const float* __restrict__ bias, const float* __restrict__ Wf,
                         const int* __restrict__ perm, const int* __restrict__ deg,
                         float* __restrict__ logits) {
    constexpr int COUT = 256;
    __shared__ _Float16 Ah[BM][KP];
    __shared__ _Float16 Al[BM][KP];
    __shared__ _Float16 Bh[256][KP];
    __shared__ _Float16 Blo[256][KP];
    __shared__ int rowid[BM];

    const int t  = threadIdx.x;
    const int m0 = blockIdx.x * BM;

    if (t < BM) rowid[t] = perm[m0 + t];
    __syncthreads();
    if (rowid[0] < 0) return;

    const int d = min(deg[rowid[0]], MAXD);
    const _Float16* WlhB = wlh + (size_t)d * 128 * COUT;
    const _Float16* WllB = wll + (size_t)d * 128 * COUT;
    const _Float16* WrhB = wrh + (size_t)d * 128 * COUT;
    const _Float16* WrlB = wrl + (size_t)d * 128 * COUT;

    const int am = t & 63, aq = t >> 6;
    const int anode = rowid[am];
    const int bn = (t & 63) * 4, bk = t >> 6;
    const int lx = t & 15, qd = (t >> 4) & 3, wv = t >> 6;

    f32x4 acc[4][4];
#pragma unroll
    for (int mt = 0; mt < 4; mt++)
#pragma unroll
        for (int nt = 0; nt < 4; nt++) acc[mt][nt] = (f32x4)0.f;

    for (int k0 = 0; k0 < 256; k0 += KT) {
        // stage A (own row, fp32 -> hi/lo)
        {
            const int gk0 = k0 + 4 * aq;
            float4 v0 = make_float4(0.f, 0.f, 0.f, 0.f);
            float4 v1 = v0;
            if (anode >= 0) {
                const float* r = (gk0 < 128) ? buf0 + (size_t)anode * 128 + gk0
                                             : buf1 + (size_t)anode * 128 + (gk0 - 128);
                v0 = *(const float4*)r;
                v1 = *(const float4*)(r + 16);
            }
            const int kk0 = 4 * aq, kk1 = kk0 + 16;
            const float g[8] = {v0.x, v0.y, v0.z, v0.w, v1.x, v1.y, v1.z, v1.w};
#pragma unroll
            for (int i = 0; i < 4; i++) {
                _Float16 h = (_Float16)g[i];
                Ah[am][kk0 + i] = h;
                Al[am][kk0 + i] = (_Float16)(g[i] - (float)h);
                h = (_Float16)g[4 + i];
                Ah[am][kk1 + i] = h;
                Al[am][kk1 + i] = (_Float16)(g[4 + i] - (float)h);
            }
        }
        // stage B
#pragma unroll
        for (int j = 0; j < 8; j++) {
            const int kk = bk + 4 * j;
            const int gk = k0 + kk;
            const _Float16* ph;
            const _Float16* pl;
            if (gk < 128) {
                ph = WlhB + (size_t)gk * COUT + bn;
                pl = WllB + (size_t)gk * COUT + bn;
            } else {
                ph = WrhB + (size_t)(gk - 128) * COUT + bn;
                pl = WrlB + (size_t)(gk - 128) * COUT + bn;
            }
            const half4 vh = *(const half4*)ph;
            const half4 vl = *(const half4*)pl;
#pragma unroll
            for (int i = 0; i < 4; i++) {
                Bh[bn + i][kk]  = vh[i];
                Blo[bn + i][kk] = vl[i];
            }
        }
        __syncthreads();
        {
            half8 ah[4], alo[4];
#pragma unroll
            for (int mt = 0; mt < 4; mt++) {
                ah[mt]  = *(const half8*)&Ah[mt * 16 + lx][qd * 8];
                alo[mt] = *(const half8*)&Al[mt * 16 + lx][qd * 8];
            }
#pragma unroll
            for (int nt = 0; nt < 4; nt++) {
                const int bcol = wv * 64 + nt * 16 + lx;
                const half8 bhv = *(const half8*)&Bh[bcol][qd * 8];
                const half8 blv = *(const half8*)&Blo[bcol][qd * 8];
#pragma unroll
                for (int mt = 0; mt < 4; mt++) {
                    acc[mt][nt] = __builtin_amdgcn_mfma_f32_16x16x32_f16(ah[mt],  bhv, acc[mt][nt], 0, 0, 0);
                    acc[mt][nt] = __builtin_amdgcn_mfma_f32_16x16x32_f16(alo[mt], bhv, acc[mt][nt], 0, 0, 0);
                    acc[mt][nt] = __builtin_amdgcn_mfma_f32_16x16x32_f16(ah[mt],  blv, acc[mt][nt], 0, 0, 0);
                }
            }
        }
        __syncthreads();
    }

    // epilogue: lane cols wv*64 + nt*16 + lx; in-place split write
    float blv[4], w0[4], w1[4];
    int cols[4];
#pragma unroll
    for (int nt = 0; nt < 4; nt++) {
        cols[nt] = wv * 64 + nt * 16 + lx;
        blv[nt] = bias[d * COUT + cols[nt]];
        w0[nt]  = Wf[(size_t)(256 + cols[nt]) * 2 + 0];
        w1[nt]  = Wf[(size_t)(256 + cols[nt]) * 2 + 1];
    }
#pragma unroll
    for (int mt = 0; mt < 4; mt++)
#pragma unroll
    for (int r = 0; r < 4; r++) {
        const int node = rowid[mt * 16 + qd * 4 + r];
        float p0 = 0.f, p1 = 0.f;
        if (node >= 0) {
#pragma unroll
            for (int nt = 0; nt < 4; nt++) {
                const float h = acc[mt][nt][r] + blv[nt];
                p0 = fmaf(h, w0[nt], p0);
                p1 = fmaf(h, w1[nt], p1);
                if (cols[nt] < 128) buf0[(size_t)node * 128 + cols[nt]] = h;
                else                buf1[(size_t)node * 128 + cols[nt] - 128] = h;
            }
        }
#pragma unroll
        for (int s = 1; s < 16; s <<= 1) {
            p0 += __shfl_xor(p0, s, 64);
            p1 += __shfl_xor(p1, s, 64);
        }
        if (node >= 0 && lx == 0) {
            atomicAdd(&logits[(size_t)node * 2 + 0], p0);
            atomicAdd(&logits[(size_t)node * 2 + 1], p1);
        }
    }
}

// ---------------- pooling / output ----------------

__global__ void k_pool_logits(const float* __restrict__ pool, const float* __restrict__ Wf,
                              const float* __restrict__ bf, float* __restrict__ pl) {
    int g = blockIdx.x * 4 + (threadIdx.x >> 6);
    int lane = threadIdx.x & 63;
    const float* pr = pool + (size_t)g * 256;
    float p0 = 0.f, p1 = 0.f;
#pragma unroll
    for (int j = 0; j < 4; j++) {
        int k = lane + 64 * j;
        float v = pr[k];
        p0 = fmaf(v, Wf[(size_t)(768 + k) * 2 + 0], p0);
        p1 = fmaf(v, Wf[(size_t)(768 + k) * 2 + 1], p1);
    }
#pragma unroll
    for (int s = 1; s < 64; s <<= 1) {
        p0 += __shfl_xor(p0, s, 64);
        p1 += __shfl_xor(p1, s, 64);
    }
    if (lane == 0) {
        pl[(size_t)g * 2 + 0] = p0 + bf[0];
        pl[(size_t)g * 2 + 1] = p1 + bf[1];
    }
}

__global__ void k_final(const float* __restrict__ logits, const float* __restrict__ pl,
                        const int* __restrict__ batch, float* __restrict__ outp) {
    int i = blockIdx.x * 256 + threadIdx.x;
    if (i < NN) {
        int g = batch[i];
        float l0 = logits[(size_t)i * 2 + 0] + pl[(size_t)g * 2 + 0];
        float l1 = logits[(size_t)i * 2 + 1] + pl[(size_t)g * 2 + 1];
        float m = fmaxf(l0, l1);
        float e0 = expf(l0 - m), e1 = expf(l1 - m);
        float inv = 1.f / (e0 + e1);
        outp[(size_t)i * 2 + 0] = e0 * inv;
        outp[(size_t)i * 2 + 1] = e1 * inv;
    }
}

}  // namespace

extern "C" void kernel_launch(void* const* d_in, const int* in_sizes, int n_in,
                              void* d_out, int out_size, void* d_ws, size_t ws_size,
                              hipStream_t stream) {
    const float* x     = (const float*)d_in[0];
    const int*   ei    = (const int*)d_in[1];
    const int*   batch = (const int*)d_in[2];
    const float* Wl0 = (const float*)d_in[3];  const float* bl0 = (const float*)d_in[4];
    const float* Wr0 = (const float*)d_in[5];
    const float* Wl1 = (const float*)d_in[6];  const float* bl1 = (const float*)d_in[7];
    const float* Wr1 = (const float*)d_in[8];
    const float* Wl2 = (const float*)d_in[9];  const float* bl2 = (const float*)d_in[10];
    const float* Wr2 = (const float*)d_in[11];
    const float* Wl3 = (const float*)d_in[12]; const float* bl3 = (const float*)d_in[13];
    const float* Wr3 = (const float*)d_in[14];
    const float* Wf  = (const float*)d_in[15]; const float* bf  = (const float*)d_in[16];
    const int* src = ei;
    const int* dst = ei + NE;
    float* outp = (float*)d_out;
    (void)in_sizes; (void)n_in;

    // workspace bump allocator (256B aligned).  Total ≈ 224 MB (ws is 256 MB).
    char* w = (char*)d_ws;
    auto alloc = [&](size_t bytes) -> void* {
        void* p = (void*)w;
        w += (bytes + 255) & ~(size_t)255;
        return p;
    };
    // zero-init region (contiguous): deg .. pool
    int*   deg    = (int*)alloc((size_t)NN * 4);
    float* logits = (float*)alloc((size_t)NN * 2 * 4);
    float* pool   = (float*)alloc((size_t)NG * 256 * 4);
    size_t zero_words = (size_t)(w - (char*)deg) / 4;
    // fully-written-by-kernel regions
    int*   bpad    = (int*)alloc(32);
    int*   blkcnt  = (int*)alloc((size_t)6 * NBC * 4);
    int*   perm    = (int*)alloc((size_t)PERMN * 4);      // filled with -1
    int*   row_ptr = (int*)alloc((size_t)(NN + 1) * 4);
    int*   cursor  = (int*)alloc((size_t)NN * 4);
    int*   col     = (int*)alloc((size_t)NE * 4);
    int*   part    = (int*)alloc(1024 * 4);
    float* pl      = (float*)alloc((size_t)NG * 2 * 4);
    _Float16* whi  = (_Float16*)alloc(WTOT * 2);          // pre-split weights hi
    _Float16* wlo  = (_Float16*)alloc(WTOT * 2);          // pre-split weights lo
    float* bufA    = (float*)alloc((size_t)NN * 128 * 4); // h0 -> m2 -> h2[:,0:128)
    float* bufB    = (float*)alloc((size_t)NN * 128 * 4); // h1 -> h2[:,128:256)

    size_t required = (size_t)(w - (char*)d_ws);
    if (required > ws_size) {
        k_report<<<(out_size + 255) / 256, 256, 0, stream>>>(
            outp, (float)(double)(ws_size >> 20), out_size);
        return;
    }

    dim3 b256(256);
    k_memset32<<<(int)((zero_words + 255) / 256), b256, 0, stream>>>((int*)deg, 0, (int)zero_words);
    k_memset32<<<(PERMN + 255) / 256, b256, 0, stream>>>(perm, -1, PERMN);

    // pre-split all weights to f16 hi/lo
    k_wsplit<<<(int)(S_L0 + 255) / 256, b256, 0, stream>>>(Wl0, whi + O_WL0, wlo + O_WL0, (int)S_L0);
    k_wsplit<<<(int)(S_L0 + 255) / 256, b256, 0, stream>>>(Wr0, whi + O_WR0, wlo + O_WR0, (int)S_L0);
    k_wsplit<<<(int)(S_L1 + 255) / 256, b256, 0, stream>>>(Wl1, whi + O_WL1, wlo + O_WL1, (int)S_L1);
    k_wsplit<<<(int)(S_L1 + 255) / 256, b256, 0, stream>>>(Wr1, whi + O_WR1, wlo + O_WR1, (int)S_L1);
    k_wsplit<<<(int)(S_L2 + 255) / 256, b256, 0, stream>>>(Wl2, whi + O_WL2, wlo + O_WL2, (int)S_L2);
    k_wsplit<<<(int)(S_L2 + 255) / 256, b256, 0, stream>>>(Wr2, whi + O_WR2, wlo + O_WR2, (int)S_L2);
    k_wsplit<<<(int)(S_L3 + 255) / 256, b256, 0, stream>>>(Wl3, whi + O_WL3, wlo + O_WL3, (int)S_L3);
    k_wsplit<<<(int)(S_L3 + 255) / 256, b256, 0, stream>>>(Wr3, whi + O_WR3, wlo + O_WR3, (int)S_L3);

    k_count_deg<<<NE / 256, b256, 0, stream>>>(dst, deg);
    k_scan_part<<<NBC, b256, 0, stream>>>(deg, part);
    k_scan_single<<<1, 1024, 0, stream>>>(part, NBC);
    k_scan_final<<<NBC, b256, 0, stream>>>(deg, part, row_ptr, cursor);
    k_fill_csr<<<NE / 256, b256, 0, stream>>>(src, dst, cursor, col);
    // two-level bucket sort (decontended)
    k_bucket_blockcount<<<NBC, b256, 0, stream>>>(deg, blkcnt);
    k_bucket_scanall<<<1, 64, 0, stream>>>(blkcnt, bpad);
    k_scatter2<<<NBC, b256, 0, stream>>>(deg, blkcnt, bpad, perm);

    // Layer 0: in=x(64) -> h0=bufA(128)
    k_transform<64, 0, 128, 128, false><<<dim3(NBLK, 1), b256, 0, stream>>>(
        x, nullptr, row_ptr, col, whi + O_WL0, wlo + O_WL0, whi + O_WR0, wlo + O_WR0,
        bl0, Wf, perm, deg, nullptr, bufA, nullptr, logits, 0);
    // Layer 1: in=bufA(128) -> h1=bufB(128)
    k_transform<128, 0, 128, 128, false><<<dim3(NBLK, 1), b256, 0, stream>>>(
        bufA, nullptr, row_ptr, col, whi + O_WL1, wlo + O_WL1, whi + O_WR1, wlo + O_WR1,
        bl1, Wf, perm, deg, nullptr, bufB, nullptr, logits, 128);
    // Layer 2a: m2 = gather-sum(h1) -> bufA
    k_aggregate128<<<NN / 4, b256, 0, stream>>>(bufB, row_ptr, col, bufA);
    // Layer 2b: h2 = [m2|h1] @ [Wl2;Wr2] + bl2, in place -> [bufA|bufB]
    k_gemm2b<<<dim3(NBLK), b256, 0, stream>>>(
        bufA, bufB, whi + O_WL2, wlo + O_WL2, whi + O_WR2, wlo + O_WR2,
        bl2, Wf, perm, deg, logits);
    // Layer 3: in=[bufA|bufB](256) -> logits chunk + pool (h3 never stored)
    k_transform<128, 128, 256, 256, true><<<dim3(NBLK, 1), b256, 0, stream>>>(
        bufA, bufB, row_ptr, col, whi + O_WL3, wlo + O_WL3, whi + O_WR3, wlo + O_WR3,
        bl3, Wf, perm, deg, batch, nullptr, pool, logits, 512);

    k_pool_logits<<<NG / 4, b256, 0, stream>>>(pool, Wf, bf, pl);
    k_final<<<NBC, b256, 0, stream>>>(logits, pl, batch, outp);
}

// Round 11
// 1492.724 us; speedup vs baseline: 3.5479x; 1.5627x over previous
//
#include <hip/hip_runtime.h>
#include <cstdint>
#include <cstddef>

namespace {

constexpr int NN   = 200000;   // nodes
constexpr int NE   = 800000;   // edges
constexpr int NG   = 4096;     // graphs
constexpr int MAXD = 5;

constexpr int BM = 64;
constexpr int KT = 32;
constexpr int NBC = (NN + 255) / 256;           // 782 preprocessing blocks
constexpr int NBLK  = (NN + BM - 1) / BM + 6;   // 3131 (bucket padding)
constexpr int PERMN = NBLK * BM;                // 200384

typedef _Float16 half8 __attribute__((ext_vector_type(8)));
typedef _Float16 half4 __attribute__((ext_vector_type(4)));
typedef float    f32x4 __attribute__((ext_vector_type(4)));

// packed-weight offsets (fragment-ordered, per layer: 6 * 2*CIN * COUT elems)
constexpr size_t P_L0 = (size_t)6 * 128 * 128;   // 98304
constexpr size_t P_L1 = (size_t)6 * 256 * 128;   // 196608
constexpr size_t P_L2 = (size_t)6 * 256 * 256;   // 393216
constexpr size_t P_L3 = (size_t)6 * 512 * 256;   // 786432
constexpr size_t O_P0 = 0;
constexpr size_t O_P1 = O_P0 + P_L0;
constexpr size_t O_P2 = O_P1 + P_L1;
constexpr size_t O_P3 = O_P2 + P_L2;
constexpr size_t WTOT = O_P3 + P_L3;             // 1,474,560 elements

// ---------------- init / diagnostic ----------------

__global__ void k_memset32(int* __restrict__ p, int v, int n) {
    int i = blockIdx.x * 256 + threadIdx.x;
    if (i < n) p[i] = v;
}

__global__ void k_report(float* __restrict__ outp, float v, int n) {
    int i = blockIdx.x * 256 + threadIdx.x;
    if (i < n) outp[i] = v;
}

// pack fp32 weights into MFMA B-fragment order, f16 hi/lo split.
// frag element (d, ti, nb, lane, j) = W[k = ti*32 + (lane>>4)*8 + j]
//                                      [n = nb*16 + (lane&15)],
// W = Wl for k < CIN else Wr[k-CIN].
template <int CIN, int COUT>
__global__ void k_wpack(const float* __restrict__ Wl, const float* __restrict__ Wr,
                        _Float16* __restrict__ hi, _Float16* __restrict__ lo) {
    constexpr int NT = CIN / 16;   // tiles over k = 2*CIN
    constexpr int NB = COUT / 16;
    const int total = 6 * NT * NB * 64;
    int idx = blockIdx.x * 256 + threadIdx.x;
    if (idx >= total) return;
    const int lane = idx & 63;
    int rest = idx >> 6;
    const int nb = rest % NB; rest /= NB;
    const int ti = rest % NT;
    const int d  = rest / NT;
    const int k0 = ti * 32 + ((lane >> 4) * 8);
    const int n  = nb * 16 + (lane & 15);
    half8 hv, lv;
#pragma unroll
    for (int j = 0; j < 8; j++) {
        const int kk = k0 + j;
        const float v = (kk < CIN)
                            ? Wl[((size_t)d * CIN + kk) * COUT + n]
                            : Wr[((size_t)d * CIN + (kk - CIN)) * COUT + n];
        const _Float16 h = (_Float16)v;
        hv[j] = h;
        lv[j] = (_Float16)(v - (float)h);
    }
    *(half8*)(hi + (size_t)idx * 8) = hv;
    *(half8*)(lo + (size_t)idx * 8) = lv;
}

// ---------------- graph preprocessing ----------------

__global__ void k_count_deg(const int* __restrict__ dst, int* __restrict__ deg) {
    int e = blockIdx.x * 256 + threadIdx.x;
    if (e < NE) atomicAdd(&deg[dst[e]], 1);
}

__global__ void k_scan_part(const int* __restrict__ deg, int* __restrict__ part) {
    __shared__ int s[256];
    int t = threadIdx.x, i = blockIdx.x * 256 + t;
    s[t] = (i < NN) ? deg[i] : 0;
    __syncthreads();
    for (int st = 128; st > 0; st >>= 1) {
        if (t < st) s[t] += s[t + st];
        __syncthreads();
    }
    if (t == 0) part[blockIdx.x] = s[0];
}

__global__ void k_scan_single(int* __restrict__ part, int nb) {
    __shared__ int s[1024];
    int t = threadIdx.x;
    int v0 = (t < nb) ? part[t] : 0;
    s[t] = v0;
    __syncthreads();
    for (int off = 1; off < 1024; off <<= 1) {
        int v = (t >= off) ? s[t - off] : 0;
        __syncthreads();
        s[t] += v;
        __syncthreads();
    }
    if (t < nb) part[t] = s[t] - v0;
}

__global__ void k_scan_final(const int* __restrict__ deg, const int* __restrict__ part,
                             int* __restrict__ row_ptr, int* __restrict__ cursor) {
    __shared__ int s[256];
    int t = threadIdx.x, i = blockIdx.x * 256 + t;
    int v0 = (i < NN) ? deg[i] : 0;
    s[t] = v0;
    __syncthreads();
    for (int off = 1; off < 256; off <<= 1) {
        int v = (t >= off) ? s[t - off] : 0;
        __syncthreads();
        s[t] += v;
        __syncthreads();
    }
    if (i < NN) {
        int excl = s[t] - v0 + part[blockIdx.x];
        row_ptr[i] = excl;
        cursor[i]  = excl;
        if (i == NN - 1) row_ptr[NN] = excl + v0;
    }
}

__global__ void k_fill_csr(const int* __restrict__ src, const int* __restrict__ dst,
                           int* __restrict__ cursor, int* __restrict__ col) {
    int e = blockIdx.x * 256 + threadIdx.x;
    if (e < NE) {
        int d = dst[e];
        int slot = atomicAdd(&cursor[d], 1);
        col[slot] = src[e];
    }
}

// -- two-level bucket counting sort (decontended; round-9 fix) --

__global__ void k_bucket_blockcount(const int* __restrict__ deg, int* __restrict__ blkcnt) {
    __shared__ int h[6];
    int t = threadIdx.x;
    if (t < 6) h[t] = 0;
    __syncthreads();
    int i = blockIdx.x * 256 + t;
    if (i < NN) atomicAdd(&h[min(deg[i], MAXD)], 1);
    __syncthreads();
    if (t < 6) blkcnt[t * NBC + blockIdx.x] = h[t];
}

__global__ void k_bucket_scanall(int* __restrict__ blkcnt, int* __restrict__ bpad) {
    __shared__ int tot[6];
    int t = threadIdx.x;
    if (t < 6) {
        int run = 0;
        for (int j = 0; j < NBC; j++) {
            int v = blkcnt[t * NBC + j];
            blkcnt[t * NBC + j] = run;
            run += v;
        }
        tot[t] = run;
    }
    __syncthreads();
    if (t == 0) {
        int off = 0;
        for (int b = 0; b < 6; b++) {
            bpad[b] = off;
            off += ((tot[b] + BM - 1) / BM) * BM;
        }
        bpad[6] = off;
    }
}

__global__ void k_scatter2(const int* __restrict__ deg, const int* __restrict__ blkcnt,
                           const int* __restrict__ bpad, int* __restrict__ perm) {
    __shared__ int base[6];
    int t = threadIdx.x;
    if (t < 6) base[t] = bpad[t] + blkcnt[t * NBC + blockIdx.x];
    __syncthreads();
    int i = blockIdx.x * 256 + t;
    if (i < NN) {
        int b = min(deg[i], MAXD);
        int pos = atomicAdd(&base[b], 1);
        perm[pos] = i;
    }
}

// ---------------- layer-2a: plain neighbor-sum aggregate ----------------

__global__ void k_aggregate128(const float* __restrict__ hin, const int* __restrict__ row_ptr,
                               const int* __restrict__ col, float* __restrict__ msg) {
    int node = blockIdx.x * 4 + (threadIdx.x >> 6);
    int lane = threadIdx.x & 63;
    int s = row_ptr[node], e = row_ptr[node + 1];
    float2 acc = make_float2(0.f, 0.f);
    for (int p = s; p < e; p++) {
        const float2 v = *(const float2*)(hin + (size_t)col[p] * 128 + lane * 2);
        acc.x += v.x; acc.y += v.y;
    }
    *(float2*)(msg + (size_t)node * 128 + lane * 2) = acc;
}

// ---------------- fused aggregate + transform (fragment-native MFMA) --------

// out[i] = [sum_{j->i} hin[j], hin[i]] @ [Wl[d]; Wr[d]] + bl[d], d = bucket(i).
// A tiles staged in LDS in MFMA-fragment order A[mt][lane][8] (writes 8B at
// 16B/lane stride = 2-way-free; reads b128 at lane*16 = bank-optimal).
// B NEVER touches LDS: waves load pre-packed half8 fragments global->reg
// (coalesced, L2-resident).  Round-10 layout cost 4e8 conflict cycles (57%).
// 3-pass f16 hi/lo split MFMA; gather prefetch pipeline retained.
template <int C0, int C1, int COUT, int BN_, bool POOL_FUSE>
__launch_bounds__(256, (BN_ == 256) ? 3 : 4)
__global__ void k_transform(const float* __restrict__ hin0, const float* __restrict__ hin1,
                            const int* __restrict__ row_ptr, const int* __restrict__ col,
                            const _Float16* __restrict__ wph, const _Float16* __restrict__ wpl,
                            const float* __restrict__ bias, const float* __restrict__ Wf,
                            const int* __restrict__ perm, const int* __restrict__ deg,
                            const int* __restrict__ batch,
                            float* __restrict__ out0, float* __restrict__ pool,
                            float* __restrict__ logits, int wf_off) {
    constexpr int CIN = C0 + C1;
    constexpr int NW0 = C0 / 32;
    constexpr int NW  = CIN / 32;
    constexpr int NT  = 2 * NW;
    constexpr int NB  = COUT / 16;
    constexpr int NTN = BN_ / 64;        // n-tiles per wave
    __shared__ _Float16 Ah[4][64][8];    // 4 KB
    __shared__ _Float16 Al[4][64][8];    // 4 KB
    __shared__ int rowid[BM];

    const int t  = threadIdx.x;
    const int m0 = blockIdx.x * BM;
    const int n0 = blockIdx.y * BN_;

    if (t < BM) rowid[t] = perm[m0 + t];
    __syncthreads();
    if (rowid[0] < 0) return;  // fully-padded block (uniform exit)

    const int d = min(deg[rowid[0]], MAXD);

    const int am = t & 63, aq = t >> 6;
    const int anode = rowid[am];
    int es = 0, ee = 0;
    if (anode >= 0) { es = row_ptr[anode]; ee = row_ptr[anode + 1]; }
    const int lx = t & 15, qd = (t >> 4) & 3, wv = t >> 6;

    // A-fragment write targets for this thread (k-slices 4aq and 16+4aq)
    const int mt_w = am >> 4;
    const int lA1  = (am & 15) + ((aq >> 1) << 4);
    const int lA2  = (am & 15) + ((2 + (aq >> 1)) << 4);
    const int j0   = (aq & 1) * 4;

    const int nb0 = n0 / 16 + wv * NTN;

    // gather A-fragment for tile ti into g[8] (constant-indexed scalars)
    auto gather = [&](int ti, float* g) {
#pragma unroll
        for (int i = 0; i < 8; i++) g[i] = 0.f;
        if (ti < NW) {
            const bool lo = (C1 == 0) || (ti < NW0);
            const float* base = lo ? hin0 : hin1;
            const int stride  = lo ? C0 : C1;
            const int off     = (lo ? 32 * ti : 32 * (ti - NW0)) + 4 * aq;
            for (int p = es; p < ee; p++) {
                const float* r = base + (size_t)col[p] * stride + off;
                const float4 a = *(const float4*)r;
                const float4 b = *(const float4*)(r + 16);
                g[0] += a.x; g[1] += a.y; g[2] += a.z; g[3] += a.w;
                g[4] += b.x; g[5] += b.y; g[6] += b.z; g[7] += b.w;
            }
        } else if (anode >= 0) {
            const int e = (ti - NW) * 32 + 4 * aq;
            const float* r = (C1 == 0 || e < C0)
                                 ? hin0 + (size_t)anode * C0 + e
                                 : hin1 + (size_t)anode * C1 + (e - C0);
            const float4 a = *(const float4*)r;
            const float4 b = *(const float4*)(r + 16);
            g[0] = a.x; g[1] = a.y; g[2] = a.z; g[3] = a.w;
            g[4] = b.x; g[5] = b.y; g[6] = b.z; g[7] = b.w;
        }
    };

    f32x4 acc[4][NTN];
#pragma unroll
    for (int mt = 0; mt < 4; mt++)
#pragma unroll
        for (int nt = 0; nt < NTN; nt++) acc[mt][nt] = (f32x4)0.f;

    float gcur[8];
    gather(0, gcur);

    for (int ti = 0; ti < NT; ti++) {
        // stage A (fp32 -> f16 hi/lo, fragment layout)
        {
            half4 h1, l1, h2, l2;
#pragma unroll
            for (int i = 0; i < 4; i++) {
                const _Float16 h = (_Float16)gcur[i];
                h1[i] = h; l1[i] = (_Float16)(gcur[i] - (float)h);
                const _Float16 g = (_Float16)gcur[4 + i];
                h2[i] = g; l2[i] = (_Float16)(gcur[4 + i] - (float)g);
            }
            *(half4*)&Ah[mt_w][lA1][j0] = h1;
            *(half4*)&Al[mt_w][lA1][j0] = l1;
            *(half4*)&Ah[mt_w][lA2][j0] = h2;
            *(half4*)&Al[mt_w][lA2][j0] = l2;
        }
        // B fragments: global -> reg (pre-packed, coalesced)
        half8 bh[NTN], bl[NTN];
        {
            const size_t tbase = (((size_t)d * NT + ti) * NB) * 512;
#pragma unroll
            for (int nt = 0; nt < NTN; nt++) {
                const size_t off = tbase + (size_t)(nb0 + nt) * 512 + (size_t)am * 8;
                bh[nt] = *(const half8*)(wph + off);
                bl[nt] = *(const half8*)(wpl + off);
            }
        }
        __syncthreads();

        // prefetch next tile's fragment (overlaps MFMA below)
        float gnext[8];
        if (ti + 1 < NT) {
            gather(ti + 1, gnext);
        } else {
#pragma unroll
            for (int i = 0; i < 8; i++) gnext[i] = 0.f;
        }

        // MFMA 3-pass over tile ti
        {
            half8 ah[4], alo[4];
#pragma unroll
            for (int mt = 0; mt < 4; mt++) {
                ah[mt]  = *(const half8*)&Ah[mt][am][0];
                alo[mt] = *(const half8*)&Al[mt][am][0];
            }
#pragma unroll
            for (int nt = 0; nt < NTN; nt++)
#pragma unroll
                for (int mt = 0; mt < 4; mt++) {
                    acc[mt][nt] = __builtin_amdgcn_mfma_f32_16x16x32_f16(ah[mt],  bh[nt], acc[mt][nt], 0, 0, 0);
                    acc[mt][nt] = __builtin_amdgcn_mfma_f32_16x16x32_f16(alo[mt], bh[nt], acc[mt][nt], 0, 0, 0);
                    acc[mt][nt] = __builtin_amdgcn_mfma_f32_16x16x32_f16(ah[mt],  bl[nt], acc[mt][nt], 0, 0, 0);
                }
        }
        __syncthreads();

#pragma unroll
        for (int i = 0; i < 8; i++) gcur[i] = gnext[i];
    }

    // epilogue: lane cols are n0 + wv*16*NTN + nt*16 + lx
    float blv[NTN], w0[NTN], w1[NTN];
    int cols[NTN];
#pragma unroll
    for (int nt = 0; nt < NTN; nt++) {
        cols[nt] = n0 + wv * (16 * NTN) + nt * 16 + lx;
        blv[nt] = bias[d * COUT + cols[nt]];
        w0[nt]  = Wf[(size_t)(wf_off + cols[nt]) * 2 + 0];
        w1[nt]  = Wf[(size_t)(wf_off + cols[nt]) * 2 + 1];
    }
#pragma unroll
    for (int mt = 0; mt < 4; mt++)
#pragma unroll
    for (int r = 0; r < 4; r++) {
        const int node = rowid[mt * 16 + qd * 4 + r];
        float p0 = 0.f, p1 = 0.f;
        if (node >= 0) {
            float h[NTN];
#pragma unroll
            for (int nt = 0; nt < NTN; nt++) {
                h[nt] = acc[mt][nt][r] + blv[nt];
                p0 = fmaf(h[nt], w0[nt], p0);
                p1 = fmaf(h[nt], w1[nt], p1);
            }
            if constexpr (POOL_FUSE) {
                float* pr = pool + (size_t)batch[node] * 256;
#pragma unroll
                for (int nt = 0; nt < NTN; nt++) atomicAdd(&pr[cols[nt]], h[nt]);
            } else {
                float* orow = out0 + (size_t)node * COUT;
#pragma unroll
                for (int nt = 0; nt < NTN; nt++) orow[cols[nt]] = h[nt];
            }
        }
#pragma unroll
        for (int s = 1; s < 16; s <<= 1) {
            p0 += __shfl_xor(p0, s, 64);
            p1 += __shfl_xor(p1, s, 64);
        }
        if (node >= 0 && lx == 0) {
            atomicAdd(&logits[(size_t)node * 2 + 0], p0);
            atomicAdd(&logits[(size_t)node * 2 + 1], p1);
        }
    }
}

// ---------------- layer-2b: full-width MFMA GEMM, in-place ----------------

__launch_bounds__(256, 3)
__global__ void k_gemm2b(float* __restrict__ buf0, float* __restrict__ buf1,
                         const _Float16* __restrict__ wph, const _Float16* __restrict__ wpl,
                         const float* __restrict__ bias, const float* __restrict__ Wf,
                         const int* __restrict__ perm, const int* __restrict__ deg,
                         float* __restrict__ logits) {
    constexpr int COUT = 256, NT = 8, NB = 16, NTN = 4;
    __shared__ _Float16 Ah[4][64][8];
    __shared__ _Float16 Al[4][64][8];
    __shared__ int rowid[BM];

    const int t  = threadIdx.x;
    const int m0 = blockIdx.x * BM;

    if (t < BM) rowid[t] = perm[m0 + t];
    __syncthreads();
    if (rowid[0] < 0) return;

    const int d = min(deg[rowid[0]], MAXD);

    const int am = t & 63, aq = t >> 6;
    const int anode = rowid[am];
    const int lx = t & 15, qd = (t >> 4) & 3, wv = t >> 6;

    const int mt_w = am >> 4;
    const int lA1  = (am & 15) + ((aq >> 1) << 4);
    const int lA2  = (am & 15) + ((2 + (aq >> 1)) << 4);
    const int j0   = (aq & 1) * 4;
    const int nb0  = wv * NTN;

    f32x4 acc[4][NTN];
#pragma unroll
    for (int mt = 0; mt < 4; mt++)
#pragma unroll
        for (int nt = 0; nt < NTN; nt++) acc[mt][nt] = (f32x4)0.f;

    for (int ti = 0; ti < NT; ti++) {
        // stage A (own row)
        {
            const int gk0 = ti * 32 + 4 * aq;
            float4 v0 = make_float4(0.f, 0.f, 0.f, 0.f);
            float4 v1 = v0;
            if (anode >= 0) {
                const float* r = (gk0 < 128) ? buf0 + (size_t)anode * 128 + gk0
                                             : buf1 + (size_t)anode * 128 + (gk0 - 128);
                v0 = *(const float4*)r;
                v1 = *(const float4*)(r + 16);
            }
            const float g[8] = {v0.x, v0.y, v0.z, v0.w, v1.x, v1.y, v1.z, v1.w};
            half4 h1, l1, h2, l2;
#pragma unroll
            for (int i = 0; i < 4; i++) {
                const _Float16 h = (_Float16)g[i];
                h1[i] = h; l1[i] = (_Float16)(g[i] - (float)h);
                const _Float16 q = (_Float16)g[4 + i];
                h2[i] = q; l2[i] = (_Float16)(g[4 + i] - (float)q);
            }
            *(half4*)&Ah[mt_w][lA1][j0] = h1;
            *(half4*)&Al[mt_w][lA1][j0] = l1;
            *(half4*)&Ah[mt_w][lA2][j0] = h2;
            *(half4*)&Al[mt_w][lA2][j0] = l2;
        }
        half8 bh[NTN], bl[NTN];
        {
            const size_t tbase = (((size_t)d * NT + ti) * NB) * 512;
#pragma unroll
            for (int nt = 0; nt < NTN; nt++) {
                const size_t off = tbase + (size_t)(nb0 + nt) * 512 + (size_t)am * 8;
                bh[nt] = *(const half8*)(wph + off);
                bl[nt] = *(const half8*)(wpl + off);
            }
        }
        __syncthreads();
        {
            half8 ah[4], alo[4];
#pragma unroll
            for (int mt = 0; mt < 4; mt++) {
                ah[mt]  = *(const half8*)&Ah[mt][am][0];
                alo[mt] = *(const half8*)&Al[mt][am][0];
            }
#pragma unroll
            for (int nt = 0; nt < NTN; nt++)
#pragma unroll
                for (int mt = 0; mt < 4; mt++) {
                    acc[mt][nt] = __builtin_amdgcn_mfma_f32_16x16x32_f16(ah[mt],  bh[nt], acc[mt][nt], 0, 0, 0);
                    acc[mt][nt] = __builtin_amdgcn_mfma_f32_16x16x32_f16(alo[mt], bh[nt], acc[mt][nt], 0, 0, 0);
                    acc[mt][nt] = __builtin_amdgcn_mfma_f32_16x16x32_f16(ah[mt],  bl[nt], acc[mt][nt], 0, 0, 0);
                }
        }
        __syncthreads();
    }

    // epilogue: in-place split write (one block owns its rows end-to-end)
    float blv[NTN], w0[NTN], w1[NTN];
    int cols[NTN];
#pragma unroll
    for (int nt = 0; nt < NTN; nt++) {
        cols[nt] = wv * 64 + nt * 16 + lx;
        blv[nt] = bias[d * COUT + cols[nt]];
        w0[nt]  = Wf[(size_t)(256 + cols[nt]) * 2 + 0];
        w1[nt]  = Wf[(size_t)(256 + cols[nt]) * 2 + 1];
    }
#pragma unroll
    for (int mt = 0; mt < 4; mt++)
#pragma unroll
    for (int r = 0; r < 4; r++) {
        const int node = rowid[mt * 16 + qd * 4 + r];
        float p0 = 0.f, p1 = 0.f;
        if (node >= 0) {
#pragma unroll
            for (int nt = 0; nt < NTN; nt++) {
                const float h = acc[mt][nt][r] + blv[nt];
                p0 = fmaf(h, w0[nt], p0);
                p1 = fmaf(h, w1[nt], p1);
                if (cols[nt] < 128) buf0[(size_t)node * 128 + cols[nt]] = h;
                else                buf1[(size_t)node * 128 + cols[nt] - 128] = h;
            }
        }
#pragma unroll
        for (int s = 1; s < 16; s <<= 1) {
            p0 += __shfl_xor(p0, s, 64);
            p1 += __shfl_xor(p1, s, 64);
        }
        if (node >= 0 && lx == 0) {
            atomicAdd(&logits[(size_t)node * 2 + 0], p0);
            atomicAdd(&logits[(size_t)node * 2 + 1], p1);
        }
    }
}

// ---------------- pooling / output ----------------

__global__ void k_pool_logits(const float* __restrict__ pool, const float* __restrict__ Wf,
                              const float* __restrict__ bf, float* __restrict__ pl) {
    int g = blockIdx.x * 4 + (threadIdx.x >> 6);
    int lane = threadIdx.x & 63;
    const float* pr = pool + (size_t)g * 256;
    float p0 = 0.f, p1 = 0.f;
#pragma unroll
    for (int j = 0; j < 4; j++) {
        int k = lane + 64 * j;
        float v = pr[k];
        p0 = fmaf(v, Wf[(size_t)(768 + k) * 2 + 0], p0);
        p1 = fmaf(v, Wf[(size_t)(768 + k) * 2 + 1], p1);
    }
#pragma unroll
    for (int s = 1; s < 64; s <<= 1) {
        p0 += __shfl_xor(p0, s, 64);
        p1 += __shfl_xor(p1, s, 64);
    }
    if (lane == 0) {
        pl[(size_t)g * 2 + 0] = p0 + bf[0];
        pl[(size_t)g * 2 + 1] = p1 + bf[1];
    }
}

__global__ void k_final(const float* __restrict__ logits, const float* __restrict__ pl,
                        const int* __restrict__ batch, float* __restrict__ outp) {
    int i = blockIdx.x * 256 + threadIdx.x;
    if (i < NN) {
        int g = batch[i];
        float l0 = logits[(size_t)i * 2 + 0] + pl[(size_t)g * 2 + 0];
        float l1 = logits[(size_t)i * 2 + 1] + pl[(size_t)g * 2 + 1];
        float m = fmaxf(l0, l1);
        float e0 = expf(l0 - m), e1 = expf(l1 - m);
        float inv = 1.f / (e0 + e1);
        outp[(size_t)i * 2 + 0] = e0 * inv;
        outp[(size_t)i * 2 + 1] = e1 * inv;
    }
}

}  // namespace

extern "C" void kernel_launch(void* const* d_in, const int* in_sizes, int n_in,
                              void* d_out, int out_size, void* d_ws, size_t ws_size,
                              hipStream_t stream) {
    const float* x     = (const float*)d_in[0];
    const int*   ei    = (const int*)d_in[1];
    const int*   batch = (const int*)d_in[2];
    const float* Wl0 = (const float*)d_in[3];  const float* bl0 = (const float*)d_in[4];
    const float* Wr0 = (const float*)d_in[5];
    const float* Wl1 = (const float*)d_in[6];  const float* bl1 = (const float*)d_in[7];
    const float* Wr1 = (const float*)d_in[8];
    const float* Wl2 = (const float*)d_in[9];  const float* bl2 = (const float*)d_in[10];
    const float* Wr2 = (const float*)d_in[11];
    const float* Wl3 = (const float*)d_in[12]; const float* bl3 = (const float*)d_in[13];
    const float* Wr3 = (const float*)d_in[14];
    const float* Wf  = (const float*)d_in[15]; const float* bf  = (const float*)d_in[16];
    const int* src = ei;
    const int* dst = ei + NE;
    float* outp = (float*)d_out;
    (void)in_sizes; (void)n_in;

    // workspace bump allocator (256B aligned).  Total ≈ 224 MB (ws is 256 MB).
    char* w = (char*)d_ws;
    auto alloc = [&](size_t bytes) -> void* {
        void* p = (void*)w;
        w += (bytes + 255) & ~(size_t)255;
        return p;
    };
    // zero-init region (contiguous): deg .. pool
    int*   deg    = (int*)alloc((size_t)NN * 4);
    float* logits = (float*)alloc((size_t)NN * 2 * 4);
    float* pool   = (float*)alloc((size_t)NG * 256 * 4);
    size_t zero_words = (size_t)(w - (char*)deg) / 4;
    // fully-written-by-kernel regions
    int*   bpad    = (int*)alloc(32);
    int*   blkcnt  = (int*)alloc((size_t)6 * NBC * 4);
    int*   perm    = (int*)alloc((size_t)PERMN * 4);      // filled with -1
    int*   row_ptr = (int*)alloc((size_t)(NN + 1) * 4);
    int*   cursor  = (int*)alloc((size_t)NN * 4);
    int*   col     = (int*)alloc((size_t)NE * 4);
    int*   part    = (int*)alloc(1024 * 4);
    float* pl      = (float*)alloc((size_t)NG * 2 * 4);
    _Float16* whi  = (_Float16*)alloc(WTOT * 2);          // packed weights hi
    _Float16* wlo  = (_Float16*)alloc(WTOT * 2);          // packed weights lo
    float* bufA    = (float*)alloc((size_t)NN * 128 * 4); // h0 -> m2 -> h2[:,0:128)
    float* bufB    = (float*)alloc((size_t)NN * 128 * 4); // h1 -> h2[:,128:256)

    size_t required = (size_t)(w - (char*)d_ws);
    if (required > ws_size) {
        k_report<<<(out_size + 255) / 256, 256, 0, stream>>>(
            outp, (float)(double)(ws_size >> 20), out_size);
        return;
    }

    dim3 b256(256);
    k_memset32<<<(int)((zero_words + 255) / 256), b256, 0, stream>>>((int*)deg, 0, (int)zero_words);
    k_memset32<<<(PERMN + 255) / 256, b256, 0, stream>>>(perm, -1, PERMN);

    // pack all weights into fragment-ordered f16 hi/lo
    k_wpack<64, 128><<<(int)(P_L0 / 8 + 255) / 256, b256, 0, stream>>>(Wl0, Wr0, whi + O_P0, wlo + O_P0);
    k_wpack<128, 128><<<(int)(P_L1 / 8 + 255) / 256, b256, 0, stream>>>(Wl1, Wr1, whi + O_P1, wlo + O_P1);
    k_wpack<128, 256><<<(int)(P_L2 / 8 + 255) / 256, b256, 0, stream>>>(Wl2, Wr2, whi + O_P2, wlo + O_P2);
    k_wpack<256, 256><<<(int)(P_L3 / 8 + 255) / 256, b256, 0, stream>>>(Wl3, Wr3, whi + O_P3, wlo + O_P3);

    k_count_deg<<<NE / 256, b256, 0, stream>>>(dst, deg);
    k_scan_part<<<NBC, b256, 0, stream>>>(deg, part);
    k_scan_single<<<1, 1024, 0, stream>>>(part, NBC);
    k_scan_final<<<NBC, b256, 0, stream>>>(deg, part, row_ptr, cursor);
    k_fill_csr<<<NE / 256, b256, 0, stream>>>(src, dst, cursor, col);
    k_bucket_blockcount<<<NBC, b256, 0, stream>>>(deg, blkcnt);
    k_bucket_scanall<<<1, 64, 0, stream>>>(blkcnt, bpad);
    k_scatter2<<<NBC, b256, 0, stream>>>(deg, blkcnt, bpad, perm);

    // Layer 0: in=x(64) -> h0=bufA(128)
    k_transform<64, 0, 128, 128, false><<<dim3(NBLK, 1), b256, 0, stream>>>(
        x, nullptr, row_ptr, col, whi + O_P0, wlo + O_P0,
        bl0, Wf, perm, deg, nullptr, bufA, nullptr, logits, 0);
    // Layer 1: in=bufA(128) -> h1=bufB(128)
    k_transform<128, 0, 128, 128, false><<<dim3(NBLK, 1), b256, 0, stream>>>(
        bufA, nullptr, row_ptr, col, whi + O_P1, wlo + O_P1,
        bl1, Wf, perm, deg, nullptr, bufB, nullptr, logits, 128);
    // Layer 2a: m2 = gather-sum(h1) -> bufA
    k_aggregate128<<<NN / 4, b256, 0, stream>>>(bufB, row_ptr, col, bufA);
    // Layer 2b: h2 = [m2|h1] @ [Wl2;Wr2] + bl2, in place -> [bufA|bufB]
    k_gemm2b<<<dim3(NBLK), b256, 0, stream>>>(
        bufA, bufB, whi + O_P2, wlo + O_P2, bl2, Wf, perm, deg, logits);
    // Layer 3: in=[bufA|bufB](256) -> logits chunk + pool (h3 never stored)
    k_transform<128, 128, 256, 256, true><<<dim3(NBLK, 1), b256, 0, stream>>>(
        bufA, bufB, row_ptr, col, whi + O_P3, wlo + O_P3,
        bl3, Wf, perm, deg, batch, nullptr, pool, logits, 512);

    k_pool_logits<<<NG / 4, b256, 0, stream>>>(pool, Wf, bf, pl);
    k_final<<<NBC, b256, 0, stream>>>(logits, pl, batch, outp);
}